// Round 1
// baseline (1010.570 us; speedup 1.0000x reference)
//
#include <hip/hip_runtime.h>
#include <math.h>

#define B_ 4
#define L_ 2048
#define D_ 1024
#define H_ 16
#define DH 64
#define NF 1025
#define BH (B_*H_)     // 64
#define NPAIR 32       // DH/2

// ---- workspace layout (in floats) ----
// z      : BH*NPAIR*L_*2 = 8388608   (packed complex pairs, in-place FFT result)
// G      : BH*2048*2     = 262144    (Hermitian-extended gate, includes 1/N)
// wscale : BH*64         = 4096      (1 + sigmoid(...))
// xbar   : B_*D_         = 4096
// part   : B_*32*D_      = 131072    (xbar partial sums)
#define Z_OFF   0
#define G_OFF   8388608
#define WSC_OFF (G_OFF + 262144)
#define XB_OFF  (WSC_OFF + 4096)
#define PART_OFF (XB_OFF + 4096)

// ---------------- xbar = mean over L of x ----------------
__global__ void k_xbar1(const float* __restrict__ x, float* __restrict__ part) {
    int t = threadIdx.x;
    int dblk = blockIdx.x;  // 0..3
    int lc = blockIdx.y;    // 0..31
    int b = blockIdx.z;     // 0..3
    int d = dblk*256 + t;
    const float* px = x + ((size_t)b*L_ + (size_t)lc*64)*D_ + d;
    float s = 0.f;
    #pragma unroll 4
    for (int l = 0; l < 64; ++l) s += px[(size_t)l*D_];
    part[(size_t)(b*32 + lc)*D_ + d] = s;
}

__global__ void k_xbar2(const float* __restrict__ part, float* __restrict__ xbar) {
    int id = blockIdx.x*256 + threadIdx.x;   // 0..4095
    int b = id >> 10, d = id & 1023;
    float s = 0.f;
    for (int c = 0; c < 32; ++c) s += part[(size_t)(b*32 + c)*D_ + d];
    xbar[id] = s * (1.0f/(float)L_);
}

// ---------------- gates: q_mean -> LN -> MLPs -> G, wscale ----------------
__global__ void k_gates(const float* __restrict__ xbar, const float* __restrict__ Wq,
                        const float* __restrict__ g_ln_w, const float* __restrict__ g_ln_b,
                        const float* __restrict__ g_w1,  const float* __restrict__ g_b1,
                        const float* __restrict__ g_w2,  const float* __restrict__ g_b2,
                        const float* __restrict__ mod_bias,
                        const float* __restrict__ w_ln_w, const float* __restrict__ w_ln_b,
                        const float* __restrict__ w_w1,  const float* __restrict__ w_b1,
                        const float* __restrict__ w_w2,  const float* __restrict__ w_b2,
                        float* __restrict__ G, float* __restrict__ wscale) {
    int bh = blockIdx.x;          // 0..63
    int b = bh >> 4, h = bh & 15;
    int t = threadIdx.x;          // 256 threads
    __shared__ float qm[64], red[256], hg[64], wh[64], h1[256], w1o[64];

    // q_mean[dh] = dot(xbar[b,:], Wq[:, h*64+dh]) ; 4 threads per dh
    {
        int dh = t & 63, partn = t >> 6;
        const float* xb = xbar + b*D_;
        const float* wq = Wq + h*DH + dh;
        float s = 0.f;
        int k0 = partn*256;
        for (int k = k0; k < k0+256; ++k) s += xb[k]*wq[(size_t)k*D_];
        red[t] = s;
    }
    __syncthreads();
    if (t < 64) qm[t] = red[t] + red[t+64] + red[t+128] + red[t+192];
    __syncthreads();

    // LN stats (computed redundantly by every thread from LDS broadcast)
    float m = 0.f;
    for (int k = 0; k < 64; ++k) m += qm[k];
    m *= (1.0f/64.0f);
    float var = 0.f;
    for (int k = 0; k < 64; ++k) { float df = qm[k]-m; var += df*df; }
    var *= (1.0f/64.0f);
    float rs = rsqrtf(var + 1e-5f);
    if (t < 64) {
        float c = (qm[t]-m)*rs;
        hg[t] = c*g_ln_w[t] + g_ln_b[t];
        wh[t] = c*w_ln_w[t] + w_ln_b[t];
    }
    __syncthreads();

    // h1 = gelu(hg @ g_w1 + g_b1)   (256 outs)
    {
        float acc = g_b1[t];
        for (int k = 0; k < 64; ++k) acc += hg[k]*g_w1[k*256 + t];
        h1[t] = 0.5f*acc*(1.0f + erff(acc*0.70710678118654752f));
    }
    // w1o = gelu(wh @ w_w1 + w_b1)  (64 outs)
    if (t < 64) {
        float acc = w_b1[t];
        for (int k = 0; k < 64; ++k) acc += wh[k]*w_w1[k*64 + t];
        w1o[t] = 0.5f*acc*(1.0f + erff(acc*0.70710678118654752f));
    }
    __syncthreads();

    // wscale = 1 + sigmoid(w1o @ w_w2 + w_b2)
    if (t < 64) {
        float acc = w_b2[t];
        for (int k = 0; k < 64; ++k) acc += w1o[k]*w_w2[k*64 + t];
        wscale[bh*64 + t] = 1.0f + 1.0f/(1.0f + expf(-acc));
    }

    // gate = h1 @ g_w2 + g_b2 ; complex modulate; write Hermitian-extended G (with 1/N folded)
    float* Gb = G + (size_t)bh*4096;
    for (int f = t; f < NF; f += 256) {
        float re = g_b2[f], im = g_b2[NF + f];
        for (int k = 0; k < 256; ++k) {
            float hv = h1[k];
            re += hv*g_w2[(size_t)k*2050 + f];
            im += hv*g_w2[(size_t)k*2050 + NF + f];
        }
        float mag = sqrtf(re*re + im*im);
        float mult = fmaxf(mag + mod_bias[f], 0.f) / (mag + 1e-6f);
        float s = mult * (1.0f/2048.0f);
        float gr = s*re, gi = s*im;
        if (f == 0 || f == 1024) gi = 0.f;   // inert imag parts -> make G exactly Hermitian
        Gb[2*f]   = gr;
        Gb[2*f+1] = gi;
        if (f >= 1 && f <= 1023) {
            Gb[2*(2048-f)]   = gr;
            Gb[2*(2048-f)+1] = -gi;
        }
    }
}

// ---------------- GEMM v = x @ Wv, scattered into packed-complex z layout ----------------
#define BM 64
#define BN 64
#define BK 16

__global__ __launch_bounds__(256) void k_gemm_v(const float* __restrict__ x,
                                                const float* __restrict__ Wv,
                                                float* __restrict__ z) {
    __shared__ float As[BM][BK+1];
    __shared__ float Bs[BK][BN+1];
    int t = threadIdx.x;
    int tx = t & 15, ty = t >> 4;
    size_t rowBase = (size_t)blockIdx.x * BM;
    int colBase = blockIdx.y * BN;
    float acc[4][4] = {};

    for (int k0 = 0; k0 < D_; k0 += BK) {
        #pragma unroll
        for (int li = t; li < BM*BK; li += 256) {
            int r = li >> 4, kk = li & 15;
            As[r][kk] = x[(rowBase + r)*D_ + k0 + kk];
        }
        #pragma unroll
        for (int li = t; li < BK*BN; li += 256) {
            int kk = li >> 6, c = li & 63;
            Bs[kk][c] = Wv[(size_t)(k0+kk)*D_ + colBase + c];
        }
        __syncthreads();
        #pragma unroll
        for (int kk = 0; kk < BK; ++kk) {
            float a0 = As[ty*4+0][kk], a1 = As[ty*4+1][kk];
            float a2 = As[ty*4+2][kk], a3 = As[ty*4+3][kk];
            float b0 = Bs[kk][tx*4+0], b1 = Bs[kk][tx*4+1];
            float b2 = Bs[kk][tx*4+2], b3 = Bs[kk][tx*4+3];
            acc[0][0]+=a0*b0; acc[0][1]+=a0*b1; acc[0][2]+=a0*b2; acc[0][3]+=a0*b3;
            acc[1][0]+=a1*b0; acc[1][1]+=a1*b1; acc[1][2]+=a1*b2; acc[1][3]+=a1*b3;
            acc[2][0]+=a2*b0; acc[2][1]+=a2*b1; acc[2][2]+=a2*b2; acc[2][3]+=a2*b3;
            acc[3][0]+=a3*b0; acc[3][1]+=a3*b1; acc[3][2]+=a3*b2; acc[3][3]+=a3*b3;
        }
        __syncthreads();
    }
    #pragma unroll
    for (int i = 0; i < 4; ++i) {
        size_t gr = rowBase + ty*4 + i;
        int b = (int)(gr >> 11);
        int l = (int)(gr & 2047);
        #pragma unroll
        for (int j = 0; j < 4; ++j) {
            int d = colBase + tx*4 + j;
            int hh = d >> 6, pr = (d >> 1) & 31, p = d & 1;
            z[((size_t)((b*16 + hh)*32 + pr)*L_ + l)*2 + p] = acc[i][j];
        }
    }
}

// ---------------- packed complex FFT-2048: fwd DIF -> gate(bitrev) -> inv DIT, in place ----------------
__global__ __launch_bounds__(256) void k_fft(float* __restrict__ z,
                                             const float* __restrict__ G,
                                             const float* __restrict__ wscale) {
    __shared__ float re[2048], im[2048];
    __shared__ float twr[1024], twi[1024];
    int t = threadIdx.x;
    int row = blockIdx.x;          // bh*32 + j
    int bh = row >> 5, j = row & 31;
    float2* zr = (float2*)z + (size_t)row * L_;

    #pragma unroll
    for (int k = 0; k < 8; ++k) {
        int i = t + k*256;
        float2 v = zr[i];
        re[i] = v.x; im[i] = v.y;
    }
    #pragma unroll
    for (int k = 0; k < 4; ++k) {
        int i = t + k*256;
        float ang = -6.283185307179586f * (float)i / 2048.0f;
        float s, c;
        sincosf(ang, &s, &c);
        twr[i] = c; twi[i] = s;
    }
    __syncthreads();

    // forward DIF (natural in -> bitrev out)
    for (int len = 1024; len >= 1; len >>= 1) {
        int step = 1024 / len;
        #pragma unroll
        for (int k = 0; k < 4; ++k) {
            int idx = t + k*256;
            int off = idx & (len-1);
            int i0 = ((idx - off) << 1) + off;
            int i1 = i0 + len;
            float ar = re[i0], ai = im[i0], br = re[i1], bi = im[i1];
            re[i0] = ar + br; im[i0] = ai + bi;
            float tr = ar - br, ti = ai - bi;
            int w = off * step;
            float wr = twr[w], wim = twi[w];
            re[i1] = tr*wr - ti*wim;
            im[i1] = tr*wim + ti*wr;
        }
        __syncthreads();
    }

    // gate multiply in bit-reversed domain
    const float* Gb = G + (size_t)bh * 4096;
    #pragma unroll
    for (int k = 0; k < 8; ++k) {
        int p = t + k*256;
        int f = (int)(__brev((unsigned)p) >> 21);
        float gr = Gb[2*f], gi = Gb[2*f+1];
        float xr = re[p], xi = im[p];
        re[p] = xr*gr - xi*gi;
        im[p] = xr*gi + xi*gr;
    }
    __syncthreads();

    // inverse DIT (bitrev in -> natural out), conj twiddles; 1/N folded in G
    for (int len = 1; len <= 1024; len <<= 1) {
        int step = 1024 / len;
        #pragma unroll
        for (int k = 0; k < 4; ++k) {
            int idx = t + k*256;
            int off = idx & (len-1);
            int i0 = ((idx - off) << 1) + off;
            int i1 = i0 + len;
            int w = off * step;
            float wr = twr[w], wim = -twi[w];
            float br = re[i1], bi = im[i1];
            float tr = br*wr - bi*wim;
            float ti = br*wim + bi*wr;
            float ar = re[i0], ai = im[i0];
            re[i0] = ar + tr; im[i0] = ai + ti;
            re[i1] = ar - tr; im[i1] = ai - ti;
        }
        __syncthreads();
    }

    float sc0 = wscale[bh*64 + 2*j];
    float sc1 = wscale[bh*64 + 2*j + 1];
    #pragma unroll
    for (int k = 0; k < 8; ++k) {
        int i = t + k*256;
        zr[i] = make_float2(re[i]*sc0, im[i]*sc1);
    }
}

// ---------------- GEMM out = vmix_scaled @ Wo (A read from z layout) ----------------
__global__ __launch_bounds__(256) void k_gemm_out(const float* __restrict__ z,
                                                  const float* __restrict__ Wo,
                                                  float* __restrict__ out) {
    __shared__ float As[BM][BK+1];
    __shared__ float Bs[BK][BN+1];
    int t = threadIdx.x;
    int tx = t & 15, ty = t >> 4;
    size_t rowBase = (size_t)blockIdx.x * BM;
    int colBase = blockIdx.y * BN;
    float acc[4][4] = {};

    for (int k0 = 0; k0 < D_; k0 += BK) {
        #pragma unroll
        for (int li = t; li < BM*BK; li += 256) {
            int r = li & 63, kk = li >> 6;
            size_t gr = rowBase + r;
            int b = (int)(gr >> 11);
            int l = (int)(gr & 2047);
            int kidx = k0 + kk;
            int hh = kidx >> 6, pr = (kidx >> 1) & 31, p = kidx & 1;
            As[r][kk] = z[((size_t)((b*16 + hh)*32 + pr)*L_ + l)*2 + p];
        }
        #pragma unroll
        for (int li = t; li < BK*BN; li += 256) {
            int kk = li >> 6, c = li & 63;
            Bs[kk][c] = Wo[(size_t)(k0+kk)*D_ + colBase + c];
        }
        __syncthreads();
        #pragma unroll
        for (int kk = 0; kk < BK; ++kk) {
            float a0 = As[ty*4+0][kk], a1 = As[ty*4+1][kk];
            float a2 = As[ty*4+2][kk], a3 = As[ty*4+3][kk];
            float b0 = Bs[kk][tx*4+0], b1 = Bs[kk][tx*4+1];
            float b2 = Bs[kk][tx*4+2], b3 = Bs[kk][tx*4+3];
            acc[0][0]+=a0*b0; acc[0][1]+=a0*b1; acc[0][2]+=a0*b2; acc[0][3]+=a0*b3;
            acc[1][0]+=a1*b0; acc[1][1]+=a1*b1; acc[1][2]+=a1*b2; acc[1][3]+=a1*b3;
            acc[2][0]+=a2*b0; acc[2][1]+=a2*b1; acc[2][2]+=a2*b2; acc[2][3]+=a2*b3;
            acc[3][0]+=a3*b0; acc[3][1]+=a3*b1; acc[3][2]+=a3*b2; acc[3][3]+=a3*b3;
        }
        __syncthreads();
    }
    #pragma unroll
    for (int i = 0; i < 4; ++i) {
        size_t gr = rowBase + ty*4 + i;
        #pragma unroll
        for (int j = 0; j < 4; ++j) {
            out[gr*D_ + colBase + tx*4 + j] = acc[i][j];
        }
    }
}

extern "C" void kernel_launch(void* const* d_in, const int* in_sizes, int n_in,
                              void* d_out, int out_size, void* d_ws, size_t ws_size,
                              hipStream_t stream) {
    const float* x      = (const float*)d_in[0];
    const float* Wq     = (const float*)d_in[1];
    const float* Wv     = (const float*)d_in[2];
    const float* Wo     = (const float*)d_in[3];
    const float* g_ln_w = (const float*)d_in[4];
    const float* g_ln_b = (const float*)d_in[5];
    const float* g_w1   = (const float*)d_in[6];
    const float* g_b1   = (const float*)d_in[7];
    const float* g_w2   = (const float*)d_in[8];
    const float* g_b2   = (const float*)d_in[9];
    const float* mod_b  = (const float*)d_in[10];
    const float* w_ln_w = (const float*)d_in[11];
    const float* w_ln_b = (const float*)d_in[12];
    const float* w_w1   = (const float*)d_in[13];
    const float* w_b1   = (const float*)d_in[14];
    const float* w_w2   = (const float*)d_in[15];
    const float* w_b2   = (const float*)d_in[16];

    float* ws   = (float*)d_ws;
    float* z    = ws + Z_OFF;
    float* G    = ws + G_OFF;
    float* wsc  = ws + WSC_OFF;
    float* xbar = ws + XB_OFF;
    float* part = ws + PART_OFF;
    float* outp = (float*)d_out;

    dim3 gx(4, 32, 4);
    k_xbar1<<<gx, 256, 0, stream>>>(x, part);
    k_xbar2<<<16, 256, 0, stream>>>(part, xbar);
    k_gates<<<64, 256, 0, stream>>>(xbar, Wq, g_ln_w, g_ln_b, g_w1, g_b1, g_w2, g_b2,
                                    mod_b, w_ln_w, w_ln_b, w_w1, w_b1, w_w2, w_b2,
                                    G, wsc);
    dim3 gg(128, 16);
    k_gemm_v<<<gg, 256, 0, stream>>>(x, Wv, z);
    k_fft<<<2048, 256, 0, stream>>>(z, G, wsc);
    k_gemm_out<<<gg, 256, 0, stream>>>(z, Wo, outp);
}

// Round 2
// 413.990 us; speedup vs baseline: 2.4410x; 2.4410x over previous
//
#include <hip/hip_runtime.h>
#include <math.h>

typedef unsigned short u16;
typedef short bf16x8 __attribute__((ext_vector_type(8)));
typedef float f32x4 __attribute__((ext_vector_type(4)));
typedef u16 u16x8 __attribute__((ext_vector_type(8)));

#define B_ 4
#define L_ 2048
#define D_ 1024
#define H_ 16
#define DH 64
#define NF 1025
#define BH (B_*H_)

// ---- workspace layout (in floats) ----
#define Z_OFF    0
#define G_OFF    8388608
#define WSC_OFF  (G_OFF + 262144)
#define XB_OFF   (WSC_OFF + 4096)
#define PART_OFF (XB_OFF + 4096)
#define XHI_OFF  (PART_OFF + 131072)            // 8.4M u16 = 4194304 floats
#define XLO_OFF  (XHI_OFF + 4194304)
#define WVH_OFF  (XLO_OFF + 4194304)            // each weight: 1M u16 = 524288 floats
#define WVL_OFF  (WVH_OFF + 524288)
#define WOH_OFF  (WVL_OFF + 524288)
#define WOL_OFF  (WOH_OFF + 524288)

__device__ __forceinline__ u16 f2bf(float f) {
    unsigned u = __float_as_uint(f);
    unsigned r = u + 0x7FFFu + ((u >> 16) & 1u);
    return (u16)(r >> 16);
}
__device__ __forceinline__ float bf2f(u16 h) { return __uint_as_float(((unsigned)h) << 16); }

// ---------------- xbar = mean over L of x ----------------
__global__ void k_xbar1(const float* __restrict__ x, float* __restrict__ part) {
    int t = threadIdx.x;
    int dblk = blockIdx.x, lc = blockIdx.y, b = blockIdx.z;
    int d = dblk*256 + t;
    const float* px = x + ((size_t)b*L_ + (size_t)lc*64)*D_ + d;
    float s = 0.f;
    #pragma unroll 4
    for (int l = 0; l < 64; ++l) s += px[(size_t)l*D_];
    part[(size_t)(b*32 + lc)*D_ + d] = s;
}

__global__ void k_xbar2(const float* __restrict__ part, float* __restrict__ xbar) {
    int id = blockIdx.x*256 + threadIdx.x;
    int b = id >> 10, d = id & 1023;
    float s = 0.f;
    for (int c = 0; c < 32; ++c) s += part[(size_t)(b*32 + c)*D_ + d];
    xbar[id] = s * (1.0f/(float)L_);
}

// ---------------- gates ----------------
__global__ void k_gates(const float* __restrict__ xbar, const float* __restrict__ Wq,
                        const float* __restrict__ g_ln_w, const float* __restrict__ g_ln_b,
                        const float* __restrict__ g_w1,  const float* __restrict__ g_b1,
                        const float* __restrict__ g_w2,  const float* __restrict__ g_b2,
                        const float* __restrict__ mod_bias,
                        const float* __restrict__ w_ln_w, const float* __restrict__ w_ln_b,
                        const float* __restrict__ w_w1,  const float* __restrict__ w_b1,
                        const float* __restrict__ w_w2,  const float* __restrict__ w_b2,
                        float* __restrict__ G, float* __restrict__ wscale) {
    int bh = blockIdx.x;
    int b = bh >> 4, h = bh & 15;
    int t = threadIdx.x;
    __shared__ float qm[64], red[256], hg[64], wh[64], h1[256], w1o[64];

    {
        int dh = t & 63, partn = t >> 6;
        const float* xb = xbar + b*D_;
        const float* wq = Wq + h*DH + dh;
        float s = 0.f;
        int k0 = partn*256;
        for (int k = k0; k < k0+256; ++k) s += xb[k]*wq[(size_t)k*D_];
        red[t] = s;
    }
    __syncthreads();
    if (t < 64) qm[t] = red[t] + red[t+64] + red[t+128] + red[t+192];
    __syncthreads();

    float m = 0.f;
    for (int k = 0; k < 64; ++k) m += qm[k];
    m *= (1.0f/64.0f);
    float var = 0.f;
    for (int k = 0; k < 64; ++k) { float df = qm[k]-m; var += df*df; }
    var *= (1.0f/64.0f);
    float rs = rsqrtf(var + 1e-5f);
    if (t < 64) {
        float c = (qm[t]-m)*rs;
        hg[t] = c*g_ln_w[t] + g_ln_b[t];
        wh[t] = c*w_ln_w[t] + w_ln_b[t];
    }
    __syncthreads();

    {
        float acc = g_b1[t];
        for (int k = 0; k < 64; ++k) acc += hg[k]*g_w1[k*256 + t];
        h1[t] = 0.5f*acc*(1.0f + erff(acc*0.70710678118654752f));
    }
    if (t < 64) {
        float acc = w_b1[t];
        for (int k = 0; k < 64; ++k) acc += wh[k]*w_w1[k*64 + t];
        w1o[t] = 0.5f*acc*(1.0f + erff(acc*0.70710678118654752f));
    }
    __syncthreads();

    if (t < 64) {
        float acc = w_b2[t];
        for (int k = 0; k < 64; ++k) acc += w1o[k]*w_w2[k*64 + t];
        wscale[bh*64 + t] = 1.0f + 1.0f/(1.0f + expf(-acc));
    }

    float* Gb = G + (size_t)bh*4096;
    for (int f = t; f < NF; f += 256) {
        float re = g_b2[f], im = g_b2[NF + f];
        for (int k = 0; k < 256; ++k) {
            float hv = h1[k];
            re += hv*g_w2[(size_t)k*2050 + f];
            im += hv*g_w2[(size_t)k*2050 + NF + f];
        }
        float mag = sqrtf(re*re + im*im);
        float mult = fmaxf(mag + mod_bias[f], 0.f) / (mag + 1e-6f);
        float s = mult * (1.0f/2048.0f);
        float gr = s*re, gi = s*im;
        if (f == 0 || f == 1024) gi = 0.f;
        Gb[2*f]   = gr;
        Gb[2*f+1] = gi;
        if (f >= 1 && f <= 1023) {
            Gb[2*(2048-f)]   = gr;
            Gb[2*(2048-f)+1] = -gi;
        }
    }
}

// ---------------- x -> bf16 hi/lo split ----------------
__global__ void k_xsplit(const float4* __restrict__ x, u16* __restrict__ hi, u16* __restrict__ lo) {
    int i = blockIdx.x*256 + threadIdx.x;  // over 2097152 float4
    float4 v = x[i];
    ushort4 h, l;
    h.x = f2bf(v.x); l.x = f2bf(v.x - bf2f(h.x));
    h.y = f2bf(v.y); l.y = f2bf(v.y - bf2f(h.y));
    h.z = f2bf(v.z); l.z = f2bf(v.z - bf2f(h.z));
    h.w = f2bf(v.w); l.w = f2bf(v.w - bf2f(h.w));
    ((ushort4*)hi)[i] = h;
    ((ushort4*)lo)[i] = l;
}

// ---------------- weight transpose + bf16 hi/lo split : W[k][n] -> Wt[n][k] ----------------
__global__ void k_wsplit(const float* __restrict__ Wv, const float* __restrict__ Wo,
                         u16* __restrict__ WvH, u16* __restrict__ WvL,
                         u16* __restrict__ WoH, u16* __restrict__ WoL) {
    const float* W = blockIdx.z ? Wo : Wv;
    u16* TH = blockIdx.z ? WoH : WvH;
    u16* TL = blockIdx.z ? WoL : WvL;
    __shared__ float tile[32][33];
    int t = threadIdx.x;
    int n0 = blockIdx.x*32, k0 = blockIdx.y*32;
    #pragma unroll
    for (int i = 0; i < 4; ++i) {
        int k = (t >> 5) + 8*i;
        tile[k][t & 31] = W[(size_t)(k0 + k)*D_ + n0 + (t & 31)];
    }
    __syncthreads();
    int n = t >> 3, kc = (t & 7)*4;
    float f0 = tile[kc+0][n], f1 = tile[kc+1][n], f2 = tile[kc+2][n], f3 = tile[kc+3][n];
    ushort4 h, l;
    h.x = f2bf(f0); l.x = f2bf(f0 - bf2f(h.x));
    h.y = f2bf(f1); l.y = f2bf(f1 - bf2f(h.y));
    h.z = f2bf(f2); l.z = f2bf(f2 - bf2f(h.z));
    h.w = f2bf(f3); l.w = f2bf(f3 - bf2f(h.w));
    *(ushort4*)&TH[(size_t)(n0 + n)*D_ + k0 + kc] = h;
    *(ushort4*)&TL[(size_t)(n0 + n)*D_ + k0 + kc] = l;
}

// ---------------- bf16x3 MFMA GEMM: C[8192 x 1024] = A[8192 x 3072seg] * Bt[1024][3072seg] ----------------
__device__ __forceinline__ void gemm_seg(const u16* __restrict__ Ag, const u16* __restrict__ Bg,
                                         u16* As, u16* Bs, f32x4 (&acc)[4][4],
                                         size_t rowBase, int colBase, int t) {
    int lane = t & 63;
    int wr = (t >> 7) & 1, wc = (t >> 6) & 1;
    int lr = lane & 15, lk = (lane >> 4) << 3;
    for (int k0 = 0; k0 < 1024; k0 += 64) {
        #pragma unroll
        for (int i = 0; i < 4; ++i) {
            int c = t + i*256;
            int r = c >> 3, ko = (c & 7) << 3;
            __builtin_amdgcn_global_load_lds(
                (const __attribute__((address_space(1))) void*)(Ag + (rowBase + (size_t)r)*D_ + k0 + ko),
                (__attribute__((address_space(3))) void*)(As + c*8), 16, 0, 0);
        }
        #pragma unroll
        for (int i = 0; i < 4; ++i) {
            int c = t + i*256;
            int r = c >> 3, ko = (c & 7) << 3;
            __builtin_amdgcn_global_load_lds(
                (const __attribute__((address_space(1))) void*)(Bg + ((size_t)colBase + r)*D_ + k0 + ko),
                (__attribute__((address_space(3))) void*)(Bs + c*8), 16, 0, 0);
        }
        __syncthreads();
        #pragma unroll
        for (int ks = 0; ks < 2; ++ks) {
            bf16x8 a[4], b[4];
            #pragma unroll
            for (int m = 0; m < 4; ++m)
                a[m] = *(const bf16x8*)(As + (wr*64 + m*16 + lr)*64 + ks*32 + lk);
            #pragma unroll
            for (int n = 0; n < 4; ++n)
                b[n] = *(const bf16x8*)(Bs + (wc*64 + n*16 + lr)*64 + ks*32 + lk);
            #pragma unroll
            for (int m = 0; m < 4; ++m) {
                #pragma unroll
                for (int n = 0; n < 4; ++n)
                    acc[m][n] = __builtin_amdgcn_mfma_f32_16x16x32_bf16(a[m], b[n], acc[m][n], 0, 0, 0);
            }
        }
        __syncthreads();
    }
}

template<int EPI>
__global__ void k_mfma_gemm(const u16* __restrict__ A0, const u16* __restrict__ A1, const u16* __restrict__ A2,
                            const u16* __restrict__ B0, const u16* __restrict__ B1, const u16* __restrict__ B2,
                            float* __restrict__ C) {
    __shared__ u16 As[128*64];
    __shared__ u16 Bs[128*64];
    int t = threadIdx.x;
    size_t rowBase = (size_t)blockIdx.x * 128;
    int colBase = blockIdx.y * 128;
    f32x4 acc[4][4] = {};

    gemm_seg(A0, B0, As, Bs, acc, rowBase, colBase, t);
    gemm_seg(A1, B1, As, Bs, acc, rowBase, colBase, t);
    gemm_seg(A2, B2, As, Bs, acc, rowBase, colBase, t);

    int lane = t & 63;
    int wr = (t >> 7) & 1, wc = (t >> 6) & 1;
    int cr = (lane >> 4) * 4, cc = lane & 15;
    if (EPI == 0) {
        #pragma unroll
        for (int m = 0; m < 4; ++m) {
            #pragma unroll
            for (int n = 0; n < 4; ++n) {
                int d = colBase + wc*64 + n*16 + cc;
                int hh = d >> 6, pr = (d >> 1) & 31, p = d & 1;
                #pragma unroll
                for (int r = 0; r < 4; ++r) {
                    size_t gr = rowBase + wr*64 + m*16 + cr + r;
                    int b = (int)(gr >> 11), l = (int)(gr & 2047);
                    C[(((size_t)((b*16 + hh)*32 + pr))*L_ + l)*2 + p] = acc[m][n][r];
                }
            }
        }
    } else {
        #pragma unroll
        for (int m = 0; m < 4; ++m) {
            #pragma unroll
            for (int n = 0; n < 4; ++n) {
                int d = colBase + wc*64 + n*16 + cc;
                #pragma unroll
                for (int r = 0; r < 4; ++r) {
                    size_t gr = rowBase + wr*64 + m*16 + cr + r;
                    C[gr*D_ + d] = acc[m][n][r];
                }
            }
        }
    }
}

// ---------------- packed complex FFT-2048 (unchanged) ----------------
__global__ __launch_bounds__(256) void k_fft(float* __restrict__ z,
                                             const float* __restrict__ G,
                                             const float* __restrict__ wscale) {
    __shared__ float re[2048], im[2048];
    __shared__ float twr[1024], twi[1024];
    int t = threadIdx.x;
    int row = blockIdx.x;
    int bh = row >> 5, j = row & 31;
    float2* zr = (float2*)z + (size_t)row * L_;

    #pragma unroll
    for (int k = 0; k < 8; ++k) {
        int i = t + k*256;
        float2 v = zr[i];
        re[i] = v.x; im[i] = v.y;
    }
    #pragma unroll
    for (int k = 0; k < 4; ++k) {
        int i = t + k*256;
        float ang = -6.283185307179586f * (float)i / 2048.0f;
        float s, c;
        sincosf(ang, &s, &c);
        twr[i] = c; twi[i] = s;
    }
    __syncthreads();

    for (int len = 1024; len >= 1; len >>= 1) {
        int step = 1024 / len;
        #pragma unroll
        for (int k = 0; k < 4; ++k) {
            int idx = t + k*256;
            int off = idx & (len-1);
            int i0 = ((idx - off) << 1) + off;
            int i1 = i0 + len;
            float ar = re[i0], ai = im[i0], br = re[i1], bi = im[i1];
            re[i0] = ar + br; im[i0] = ai + bi;
            float tr = ar - br, ti = ai - bi;
            int w = off * step;
            float wr_ = twr[w], wim = twi[w];
            re[i1] = tr*wr_ - ti*wim;
            im[i1] = tr*wim + ti*wr_;
        }
        __syncthreads();
    }

    const float* Gb = G + (size_t)bh * 4096;
    #pragma unroll
    for (int k = 0; k < 8; ++k) {
        int p = t + k*256;
        int f = (int)(__brev((unsigned)p) >> 21);
        float gr = Gb[2*f], gi = Gb[2*f+1];
        float xr = re[p], xi = im[p];
        re[p] = xr*gr - xi*gi;
        im[p] = xr*gi + xi*gr;
    }
    __syncthreads();

    for (int len = 1; len <= 1024; len <<= 1) {
        int step = 1024 / len;
        #pragma unroll
        for (int k = 0; k < 4; ++k) {
            int idx = t + k*256;
            int off = idx & (len-1);
            int i0 = ((idx - off) << 1) + off;
            int i1 = i0 + len;
            int w = off * step;
            float wr_ = twr[w], wim = -twi[w];
            float br = re[i1], bi = im[i1];
            float tr = br*wr_ - bi*wim;
            float ti = br*wim + bi*wr_;
            float ar = re[i0], ai = im[i0];
            re[i0] = ar + tr; im[i0] = ai + ti;
            re[i1] = ar - tr; im[i1] = ai - ti;
        }
        __syncthreads();
    }

    float sc0 = wscale[bh*64 + 2*j];
    float sc1 = wscale[bh*64 + 2*j + 1];
    #pragma unroll
    for (int k = 0; k < 8; ++k) {
        int i = t + k*256;
        zr[i] = make_float2(re[i]*sc0, im[i]*sc1);
    }
}

// ---------------- z (fp32, packed layout) -> vmix [m][d] bf16 hi/lo ----------------
__global__ void k_vsplit(const float* __restrict__ z, u16* __restrict__ vhi, u16* __restrict__ vlo) {
    int t = threadIdx.x;
    int lt = blockIdx.x, h = blockIdx.y, b = blockIdx.z;
    int l0 = lt*64;
    __shared__ float tile[64][65];
    const float2* zb = (const float2*)z + (size_t)(b*16 + h)*32*L_;
    int pr = t >> 3, lg = t & 7;
    #pragma unroll
    for (int i = 0; i < 8; ++i) {
        int l = lg*8 + i;
        float2 v = zb[(size_t)pr*L_ + l0 + l];
        tile[l][2*pr]   = v.x;
        tile[l][2*pr+1] = v.y;
    }
    __syncthreads();
    int l = t >> 2, d0 = (t & 3) * 16;
    u16x8 h0, h1v, l0v, l1v;
    #pragma unroll
    for (int i = 0; i < 8; ++i) {
        float f = tile[l][d0+i];
        u16 hb = f2bf(f);
        h0[i] = hb; l0v[i] = f2bf(f - bf2f(hb));
    }
    #pragma unroll
    for (int i = 0; i < 8; ++i) {
        float f = tile[l][d0+8+i];
        u16 hb = f2bf(f);
        h1v[i] = hb; l1v[i] = f2bf(f - bf2f(hb));
    }
    size_t base = ((size_t)(b*L_) + l0 + l)*D_ + h*64 + d0;
    *(u16x8*)&vhi[base]   = h0;
    *(u16x8*)&vhi[base+8] = h1v;
    *(u16x8*)&vlo[base]   = l0v;
    *(u16x8*)&vlo[base+8] = l1v;
}

extern "C" void kernel_launch(void* const* d_in, const int* in_sizes, int n_in,
                              void* d_out, int out_size, void* d_ws, size_t ws_size,
                              hipStream_t stream) {
    const float* x      = (const float*)d_in[0];
    const float* Wq     = (const float*)d_in[1];
    const float* Wv     = (const float*)d_in[2];
    const float* Wo     = (const float*)d_in[3];
    const float* g_ln_w = (const float*)d_in[4];
    const float* g_ln_b = (const float*)d_in[5];
    const float* g_w1   = (const float*)d_in[6];
    const float* g_b1   = (const float*)d_in[7];
    const float* g_w2   = (const float*)d_in[8];
    const float* g_b2   = (const float*)d_in[9];
    const float* mod_b  = (const float*)d_in[10];
    const float* w_ln_w = (const float*)d_in[11];
    const float* w_ln_b = (const float*)d_in[12];
    const float* w_w1   = (const float*)d_in[13];
    const float* w_b1   = (const float*)d_in[14];
    const float* w_w2   = (const float*)d_in[15];
    const float* w_b2   = (const float*)d_in[16];

    float* ws   = (float*)d_ws;
    float* z    = ws + Z_OFF;
    float* G    = ws + G_OFF;
    float* wsc  = ws + WSC_OFF;
    float* xbar = ws + XB_OFF;
    float* part = ws + PART_OFF;
    u16* xhi = (u16*)(ws + XHI_OFF);
    u16* xlo = (u16*)(ws + XLO_OFF);
    u16* WvH = (u16*)(ws + WVH_OFF);
    u16* WvL = (u16*)(ws + WVL_OFF);
    u16* WoH = (u16*)(ws + WOH_OFF);
    u16* WoL = (u16*)(ws + WOL_OFF);
    // vmix hi/lo alias the x hi/lo buffers (x consumed by gemm1 before vsplit runs)
    u16* vhi = xhi;
    u16* vlo = xlo;
    float* outp = (float*)d_out;

    dim3 gx(4, 32, 4);
    k_xbar1<<<gx, 256, 0, stream>>>(x, part);
    k_xbar2<<<16, 256, 0, stream>>>(part, xbar);
    k_gates<<<64, 256, 0, stream>>>(xbar, Wq, g_ln_w, g_ln_b, g_w1, g_b1, g_w2, g_b2,
                                    mod_b, w_ln_w, w_ln_b, w_w1, w_b1, w_w2, w_b2,
                                    G, wsc);
    k_xsplit<<<8192, 256, 0, stream>>>((const float4*)x, xhi, xlo);
    dim3 gw(32, 32, 2);
    k_wsplit<<<gw, 256, 0, stream>>>(Wv, Wo, WvH, WvL, WoH, WoL);

    dim3 gg(64, 8);
    k_mfma_gemm<0><<<gg, 256, 0, stream>>>(xhi, xhi, xlo, WvH, WvL, WvH, z);
    k_fft<<<2048, 256, 0, stream>>>(z, G, wsc);
    dim3 gv(32, 16, 4);
    k_vsplit<<<gv, 256, 0, stream>>>(z, vhi, vlo);
    k_mfma_gemm<1><<<gg, 256, 0, stream>>>(vhi, vhi, vlo, WoH, WoL, WoH, outp);
}

// Round 3
// 372.732 us; speedup vs baseline: 2.7113x; 1.1107x over previous
//
#include <hip/hip_runtime.h>
#include <math.h>

typedef unsigned short u16;
typedef short bf16x8 __attribute__((ext_vector_type(8)));
typedef float f32x4 __attribute__((ext_vector_type(4)));
typedef u16 u16x8 __attribute__((ext_vector_type(8)));

#define B_ 4
#define L_ 2048
#define D_ 1024
#define H_ 16
#define DH 64
#define NF 1025
#define BH (B_*H_)

// ---- workspace layout (in floats) ----
#define Z_OFF    0
#define G_OFF    8388608
#define WSC_OFF  (G_OFF + 262144)
#define XB_OFF   (WSC_OFF + 4096)
#define PART_OFF (XB_OFF + 4096)
#define H1_OFF   (PART_OFF + 131072)            // 64*256 = 16384
#define XHI_OFF  (H1_OFF + 16384)
#define XLO_OFF  (XHI_OFF + 4194304)
#define WVH_OFF  (XLO_OFF + 4194304)
#define WVL_OFF  (WVH_OFF + 524288)
#define WOH_OFF  (WVL_OFF + 524288)
#define WOL_OFF  (WOH_OFF + 524288)

__device__ __forceinline__ u16 f2bf(float f) {
    unsigned u = __float_as_uint(f);
    unsigned r = u + 0x7FFFu + ((u >> 16) & 1u);
    return (u16)(r >> 16);
}
__device__ __forceinline__ float bf2f(u16 h) { return __uint_as_float(((unsigned)h) << 16); }

// ---------------- xbar = mean over L of x ----------------
__global__ void k_xbar1(const float* __restrict__ x, float* __restrict__ part) {
    int t = threadIdx.x;
    int dblk = blockIdx.x, lc = blockIdx.y, b = blockIdx.z;
    int d = dblk*256 + t;
    const float* px = x + ((size_t)b*L_ + (size_t)lc*64)*D_ + d;
    float s = 0.f;
    #pragma unroll 4
    for (int l = 0; l < 64; ++l) s += px[(size_t)l*D_];
    part[(size_t)(b*32 + lc)*D_ + d] = s;
}

__global__ void k_xbar2(const float* __restrict__ part, float* __restrict__ xbar) {
    int id = blockIdx.x*256 + threadIdx.x;
    int b = id >> 10, d = id & 1023;
    float s = 0.f;
    for (int c = 0; c < 32; ++c) s += part[(size_t)(b*32 + c)*D_ + d];
    xbar[id] = s * (1.0f/(float)L_);
}

// ---------------- gates part A: q_mean -> LN -> MLPs -> h1, wscale ----------------
__global__ void k_gates_a(const float* __restrict__ xbar, const float* __restrict__ Wq,
                          const float* __restrict__ g_ln_w, const float* __restrict__ g_ln_b,
                          const float* __restrict__ g_w1,  const float* __restrict__ g_b1,
                          const float* __restrict__ w_ln_w, const float* __restrict__ w_ln_b,
                          const float* __restrict__ w_w1,  const float* __restrict__ w_b1,
                          const float* __restrict__ w_w2,  const float* __restrict__ w_b2,
                          float* __restrict__ h1_out, float* __restrict__ wscale) {
    int bh = blockIdx.x;
    int b = bh >> 4, h = bh & 15;
    int t = threadIdx.x;
    __shared__ float qm[64], red[256], hg[64], wh[64], w1o[64];

    {
        int dh = t & 63, partn = t >> 6;
        const float* xb = xbar + b*D_;
        const float* wq = Wq + h*DH + dh;
        float s = 0.f;
        int k0 = partn*256;
        for (int k = k0; k < k0+256; ++k) s += xb[k]*wq[(size_t)k*D_];
        red[t] = s;
    }
    __syncthreads();
    if (t < 64) qm[t] = red[t] + red[t+64] + red[t+128] + red[t+192];
    __syncthreads();

    float m = 0.f;
    for (int k = 0; k < 64; ++k) m += qm[k];
    m *= (1.0f/64.0f);
    float var = 0.f;
    for (int k = 0; k < 64; ++k) { float df = qm[k]-m; var += df*df; }
    var *= (1.0f/64.0f);
    float rs = rsqrtf(var + 1e-5f);
    if (t < 64) {
        float c = (qm[t]-m)*rs;
        hg[t] = c*g_ln_w[t] + g_ln_b[t];
        wh[t] = c*w_ln_w[t] + w_ln_b[t];
    }
    __syncthreads();

    {
        float acc = g_b1[t];
        for (int k = 0; k < 64; ++k) acc += hg[k]*g_w1[k*256 + t];
        h1_out[bh*256 + t] = 0.5f*acc*(1.0f + erff(acc*0.70710678118654752f));
    }
    if (t < 64) {
        float acc = w_b1[t];
        for (int k = 0; k < 64; ++k) acc += wh[k]*w_w1[k*64 + t];
        w1o[t] = 0.5f*acc*(1.0f + erff(acc*0.70710678118654752f));
    }
    __syncthreads();

    if (t < 64) {
        float acc = w_b2[t];
        for (int k = 0; k < 64; ++k) acc += w1o[k]*w_w2[k*64 + t];
        wscale[bh*64 + t] = 1.0f + 1.0f/(1.0f + expf(-acc));
    }
}

// ---------------- gates part B: G = herm-extend(modulate(h1 @ g_w2 + g_b2)) ----------------
__global__ __launch_bounds__(256) void k_gate_g(const float* __restrict__ h1_ws,
                                                const float* __restrict__ g_w2,
                                                const float* __restrict__ g_b2,
                                                const float* __restrict__ mod_bias,
                                                float* __restrict__ G) {
    int bh = blockIdx.y;
    int f = blockIdx.x*256 + threadIdx.x;
    __shared__ float h1[256];
    h1[threadIdx.x] = h1_ws[bh*256 + threadIdx.x];
    __syncthreads();
    if (f >= NF) return;

    float re = g_b2[f], im = g_b2[NF + f];
    #pragma unroll 4
    for (int k = 0; k < 256; ++k) {
        float hv = h1[k];
        re += hv*g_w2[(size_t)k*2050 + f];
        im += hv*g_w2[(size_t)k*2050 + NF + f];
    }
    float mag = sqrtf(re*re + im*im);
    float mult = fmaxf(mag + mod_bias[f], 0.f) / (mag + 1e-6f);
    float s = mult * (1.0f/2048.0f);
    float gr = s*re, gi = s*im;
    if (f == 0 || f == 1024) gi = 0.f;
    float* Gb = G + (size_t)bh*4096;
    Gb[2*f]   = gr;
    Gb[2*f+1] = gi;
    if (f >= 1 && f <= 1023) {
        Gb[2*(2048-f)]   = gr;
        Gb[2*(2048-f)+1] = -gi;
    }
}

// ---------------- x -> bf16 hi/lo split ----------------
__global__ void k_xsplit(const float4* __restrict__ x, u16* __restrict__ hi, u16* __restrict__ lo) {
    int i = blockIdx.x*256 + threadIdx.x;
    float4 v = x[i];
    ushort4 h, l;
    h.x = f2bf(v.x); l.x = f2bf(v.x - bf2f(h.x));
    h.y = f2bf(v.y); l.y = f2bf(v.y - bf2f(h.y));
    h.z = f2bf(v.z); l.z = f2bf(v.z - bf2f(h.z));
    h.w = f2bf(v.w); l.w = f2bf(v.w - bf2f(h.w));
    ((ushort4*)hi)[i] = h;
    ((ushort4*)lo)[i] = l;
}

// ---------------- weight transpose + bf16 hi/lo split : W[k][n] -> Wt[n][k] ----------------
__global__ void k_wsplit(const float* __restrict__ Wv, const float* __restrict__ Wo,
                         u16* __restrict__ WvH, u16* __restrict__ WvL,
                         u16* __restrict__ WoH, u16* __restrict__ WoL) {
    const float* W = blockIdx.z ? Wo : Wv;
    u16* TH = blockIdx.z ? WoH : WvH;
    u16* TL = blockIdx.z ? WoL : WvL;
    __shared__ float tile[32][33];
    int t = threadIdx.x;
    int n0 = blockIdx.x*32, k0 = blockIdx.y*32;
    #pragma unroll
    for (int i = 0; i < 4; ++i) {
        int k = (t >> 5) + 8*i;
        tile[k][t & 31] = W[(size_t)(k0 + k)*D_ + n0 + (t & 31)];
    }
    __syncthreads();
    int n = t >> 3, kc = (t & 7)*4;
    float f0 = tile[kc+0][n], f1 = tile[kc+1][n], f2 = tile[kc+2][n], f3 = tile[kc+3][n];
    ushort4 h, l;
    h.x = f2bf(f0); l.x = f2bf(f0 - bf2f(h.x));
    h.y = f2bf(f1); l.y = f2bf(f1 - bf2f(h.y));
    h.z = f2bf(f2); l.z = f2bf(f2 - bf2f(h.z));
    h.w = f2bf(f3); l.w = f2bf(f3 - bf2f(h.w));
    *(ushort4*)&TH[(size_t)(n0 + n)*D_ + k0 + kc] = h;
    *(ushort4*)&TL[(size_t)(n0 + n)*D_ + k0 + kc] = l;
}

// ---------------- bf16x3 MFMA GEMM ----------------
__device__ __forceinline__ void gemm_seg(const u16* __restrict__ Ag, const u16* __restrict__ Bg,
                                         u16* As, u16* Bs, f32x4 (&acc)[4][4],
                                         size_t rowBase, int colBase, int t) {
    int lane = t & 63;
    int wr = (t >> 7) & 1, wc = (t >> 6) & 1;
    int lr = lane & 15, lk = (lane >> 4) << 3;
    for (int k0 = 0; k0 < 1024; k0 += 64) {
        #pragma unroll
        for (int i = 0; i < 4; ++i) {
            int c = t + i*256;
            int r = c >> 3, ko = (c & 7) << 3;
            __builtin_amdgcn_global_load_lds(
                (const __attribute__((address_space(1))) void*)(Ag + (rowBase + (size_t)r)*D_ + k0 + ko),
                (__attribute__((address_space(3))) void*)(As + c*8), 16, 0, 0);
        }
        #pragma unroll
        for (int i = 0; i < 4; ++i) {
            int c = t + i*256;
            int r = c >> 3, ko = (c & 7) << 3;
            __builtin_amdgcn_global_load_lds(
                (const __attribute__((address_space(1))) void*)(Bg + ((size_t)colBase + r)*D_ + k0 + ko),
                (__attribute__((address_space(3))) void*)(Bs + c*8), 16, 0, 0);
        }
        __syncthreads();
        #pragma unroll
        for (int ks = 0; ks < 2; ++ks) {
            bf16x8 a[4], b[4];
            #pragma unroll
            for (int m = 0; m < 4; ++m)
                a[m] = *(const bf16x8*)(As + (wr*64 + m*16 + lr)*64 + ks*32 + lk);
            #pragma unroll
            for (int n = 0; n < 4; ++n)
                b[n] = *(const bf16x8*)(Bs + (wc*64 + n*16 + lr)*64 + ks*32 + lk);
            #pragma unroll
            for (int m = 0; m < 4; ++m) {
                #pragma unroll
                for (int n = 0; n < 4; ++n)
                    acc[m][n] = __builtin_amdgcn_mfma_f32_16x16x32_bf16(a[m], b[n], acc[m][n], 0, 0, 0);
            }
        }
        __syncthreads();
    }
}

template<int EPI>
__global__ void k_mfma_gemm(const u16* __restrict__ A0, const u16* __restrict__ A1, const u16* __restrict__ A2,
                            const u16* __restrict__ B0, const u16* __restrict__ B1, const u16* __restrict__ B2,
                            float* __restrict__ C) {
    __shared__ u16 As[128*64];
    __shared__ u16 Bs[128*64];
    int t = threadIdx.x;
    size_t rowBase = (size_t)blockIdx.x * 128;
    int colBase = blockIdx.y * 128;
    f32x4 acc[4][4] = {};

    gemm_seg(A0, B0, As, Bs, acc, rowBase, colBase, t);
    gemm_seg(A1, B1, As, Bs, acc, rowBase, colBase, t);
    gemm_seg(A2, B2, As, Bs, acc, rowBase, colBase, t);

    int lane = t & 63;
    int wr = (t >> 7) & 1, wc = (t >> 6) & 1;
    int cr = (lane >> 4) * 4, cc = lane & 15;
    if (EPI == 0) {
        #pragma unroll
        for (int m = 0; m < 4; ++m) {
            #pragma unroll
            for (int n = 0; n < 4; ++n) {
                int d = colBase + wc*64 + n*16 + cc;
                int hh = d >> 6, pr = (d >> 1) & 31, p = d & 1;
                #pragma unroll
                for (int r = 0; r < 4; ++r) {
                    size_t gr = rowBase + wr*64 + m*16 + cr + r;
                    int b = (int)(gr >> 11), l = (int)(gr & 2047);
                    C[(((size_t)((b*16 + hh)*32 + pr))*L_ + l)*2 + p] = acc[m][n][r];
                }
            }
        }
    } else {
        #pragma unroll
        for (int m = 0; m < 4; ++m) {
            #pragma unroll
            for (int n = 0; n < 4; ++n) {
                int d = colBase + wc*64 + n*16 + cc;
                #pragma unroll
                for (int r = 0; r < 4; ++r) {
                    size_t gr = rowBase + wr*64 + m*16 + cr + r;
                    C[gr*D_ + d] = acc[m][n][r];
                }
            }
        }
    }
}

// ---------------- packed complex FFT-2048 ----------------
__global__ __launch_bounds__(256) void k_fft(float* __restrict__ z,
                                             const float* __restrict__ G,
                                             const float* __restrict__ wscale) {
    __shared__ float re[2048], im[2048];
    __shared__ float twr[1024], twi[1024];
    int t = threadIdx.x;
    int row = blockIdx.x;
    int bh = row >> 5, j = row & 31;
    float2* zr = (float2*)z + (size_t)row * L_;

    #pragma unroll
    for (int k = 0; k < 8; ++k) {
        int i = t + k*256;
        float2 v = zr[i];
        re[i] = v.x; im[i] = v.y;
    }
    #pragma unroll
    for (int k = 0; k < 4; ++k) {
        int i = t + k*256;
        float ang = -6.283185307179586f * (float)i / 2048.0f;
        float s, c;
        sincosf(ang, &s, &c);
        twr[i] = c; twi[i] = s;
    }
    __syncthreads();

    for (int len = 1024; len >= 1; len >>= 1) {
        int step = 1024 / len;
        #pragma unroll
        for (int k = 0; k < 4; ++k) {
            int idx = t + k*256;
            int off = idx & (len-1);
            int i0 = ((idx - off) << 1) + off;
            int i1 = i0 + len;
            float ar = re[i0], ai = im[i0], br = re[i1], bi = im[i1];
            re[i0] = ar + br; im[i0] = ai + bi;
            float tr = ar - br, ti = ai - bi;
            int w = off * step;
            float wr_ = twr[w], wim = twi[w];
            re[i1] = tr*wr_ - ti*wim;
            im[i1] = tr*wim + ti*wr_;
        }
        __syncthreads();
    }

    const float* Gb = G + (size_t)bh * 4096;
    #pragma unroll
    for (int k = 0; k < 8; ++k) {
        int p = t + k*256;
        int f = (int)(__brev((unsigned)p) >> 21);
        float gr = Gb[2*f], gi = Gb[2*f+1];
        float xr = re[p], xi = im[p];
        re[p] = xr*gr - xi*gi;
        im[p] = xr*gi + xi*gr;
    }
    __syncthreads();

    for (int len = 1; len <= 1024; len <<= 1) {
        int step = 1024 / len;
        #pragma unroll
        for (int k = 0; k < 4; ++k) {
            int idx = t + k*256;
            int off = idx & (len-1);
            int i0 = ((idx - off) << 1) + off;
            int i1 = i0 + len;
            int w = off * step;
            float wr_ = twr[w], wim = -twi[w];
            float br = re[i1], bi = im[i1];
            float tr = br*wr_ - bi*wim;
            float ti = br*wim + bi*wr_;
            float ar = re[i0], ai = im[i0];
            re[i0] = ar + tr; im[i0] = ai + ti;
            re[i1] = ar - tr; im[i1] = ai - ti;
        }
        __syncthreads();
    }

    float sc0 = wscale[bh*64 + 2*j];
    float sc1 = wscale[bh*64 + 2*j + 1];
    #pragma unroll
    for (int k = 0; k < 8; ++k) {
        int i = t + k*256;
        zr[i] = make_float2(re[i]*sc0, im[i]*sc1);
    }
}

// ---------------- z (fp32, packed layout) -> vmix [m][d] bf16 hi/lo ----------------
__global__ void k_vsplit(const float* __restrict__ z, u16* __restrict__ vhi, u16* __restrict__ vlo) {
    int t = threadIdx.x;
    int lt = blockIdx.x, h = blockIdx.y, b = blockIdx.z;
    int l0 = lt*64;
    __shared__ float tile[64][65];
    const float2* zb = (const float2*)z + (size_t)(b*16 + h)*32*L_;
    int pr = t >> 3, lg = t & 7;
    #pragma unroll
    for (int i = 0; i < 8; ++i) {
        int l = lg*8 + i;
        float2 v = zb[(size_t)pr*L_ + l0 + l];
        tile[l][2*pr]   = v.x;
        tile[l][2*pr+1] = v.y;
    }
    __syncthreads();
    int l = t >> 2, d0 = (t & 3) * 16;
    u16x8 h0, h1v, l0v, l1v;
    #pragma unroll
    for (int i = 0; i < 8; ++i) {
        float f = tile[l][d0+i];
        u16 hb = f2bf(f);
        h0[i] = hb; l0v[i] = f2bf(f - bf2f(hb));
    }
    #pragma unroll
    for (int i = 0; i < 8; ++i) {
        float f = tile[l][d0+8+i];
        u16 hb = f2bf(f);
        h1v[i] = hb; l1v[i] = f2bf(f - bf2f(hb));
    }
    size_t base = ((size_t)(b*L_) + l0 + l)*D_ + h*64 + d0;
    *(u16x8*)&vhi[base]   = h0;
    *(u16x8*)&vhi[base+8] = h1v;
    *(u16x8*)&vlo[base]   = l0v;
    *(u16x8*)&vlo[base+8] = l1v;
}

extern "C" void kernel_launch(void* const* d_in, const int* in_sizes, int n_in,
                              void* d_out, int out_size, void* d_ws, size_t ws_size,
                              hipStream_t stream) {
    const float* x      = (const float*)d_in[0];
    const float* Wq     = (const float*)d_in[1];
    const float* Wv     = (const float*)d_in[2];
    const float* Wo     = (const float*)d_in[3];
    const float* g_ln_w = (const float*)d_in[4];
    const float* g_ln_b = (const float*)d_in[5];
    const float* g_w1   = (const float*)d_in[6];
    const float* g_b1   = (const float*)d_in[7];
    const float* g_w2   = (const float*)d_in[8];
    const float* g_b2   = (const float*)d_in[9];
    const float* mod_b  = (const float*)d_in[10];
    const float* w_ln_w = (const float*)d_in[11];
    const float* w_ln_b = (const float*)d_in[12];
    const float* w_w1   = (const float*)d_in[13];
    const float* w_b1   = (const float*)d_in[14];
    const float* w_w2   = (const float*)d_in[15];
    const float* w_b2   = (const float*)d_in[16];

    float* ws   = (float*)d_ws;
    float* z    = ws + Z_OFF;
    float* G    = ws + G_OFF;
    float* wsc  = ws + WSC_OFF;
    float* xbar = ws + XB_OFF;
    float* part = ws + PART_OFF;
    float* h1ws = ws + H1_OFF;
    u16* xhi = (u16*)(ws + XHI_OFF);
    u16* xlo = (u16*)(ws + XLO_OFF);
    u16* WvH = (u16*)(ws + WVH_OFF);
    u16* WvL = (u16*)(ws + WVL_OFF);
    u16* WoH = (u16*)(ws + WOH_OFF);
    u16* WoL = (u16*)(ws + WOL_OFF);
    u16* vhi = xhi;
    u16* vlo = xlo;
    float* outp = (float*)d_out;

    dim3 gx(4, 32, 4);
    k_xbar1<<<gx, 256, 0, stream>>>(x, part);
    k_xbar2<<<16, 256, 0, stream>>>(part, xbar);
    k_gates_a<<<64, 256, 0, stream>>>(xbar, Wq, g_ln_w, g_ln_b, g_w1, g_b1,
                                      w_ln_w, w_ln_b, w_w1, w_b1, w_w2, w_b2,
                                      h1ws, wsc);
    dim3 ggate(5, 64);
    k_gate_g<<<ggate, 256, 0, stream>>>(h1ws, g_w2, g_b2, mod_b, G);
    k_xsplit<<<8192, 256, 0, stream>>>((const float4*)x, xhi, xlo);
    dim3 gw(32, 32, 2);
    k_wsplit<<<gw, 256, 0, stream>>>(Wv, Wo, WvH, WvL, WoH, WoL);

    dim3 gg(64, 8);
    k_mfma_gemm<0><<<gg, 256, 0, stream>>>(xhi, xhi, xlo, WvH, WvL, WvH, z);
    k_fft<<<2048, 256, 0, stream>>>(z, G, wsc);
    dim3 gv(32, 16, 4);
    k_vsplit<<<gv, 256, 0, stream>>>(z, vhi, vlo);
    k_mfma_gemm<1><<<gg, 256, 0, stream>>>(vhi, vhi, vlo, WoH, WoL, WoH, outp);
}

// Round 4
// 322.915 us; speedup vs baseline: 3.1295x; 1.1543x over previous
//
#include <hip/hip_runtime.h>
#include <math.h>

typedef unsigned short u16;
typedef short bf16x8 __attribute__((ext_vector_type(8)));
typedef float f32x4 __attribute__((ext_vector_type(4)));
typedef u16 u16x8 __attribute__((ext_vector_type(8)));

#define B_ 4
#define L_ 2048
#define D_ 1024
#define H_ 16
#define DH 64
#define NF 1025
#define BH (B_*H_)

// ---- workspace layout (in floats) ----
#define Z_OFF    0
#define G_OFF    8388608
#define WSC_OFF  (G_OFF + 262144)
#define XB_OFF   (WSC_OFF + 4096)
#define PART_OFF (XB_OFF + 4096)
#define H1_OFF   (PART_OFF + 131072)
#define QP_OFF   (H1_OFF + 16384)               // 8*4*1024 = 32768
#define XHI_OFF  (QP_OFF + 32768)
#define XLO_OFF  (XHI_OFF + 4194304)
#define WVH_OFF  (XLO_OFF + 4194304)
#define WVL_OFF  (WVH_OFF + 524288)
#define WOH_OFF  (WVL_OFF + 524288)
#define WOL_OFF  (WOH_OFF + 524288)

__device__ __forceinline__ u16 f2bf(float f) {
    unsigned u = __float_as_uint(f);
    unsigned r = u + 0x7FFFu + ((u >> 16) & 1u);
    return (u16)(r >> 16);
}
__device__ __forceinline__ float bf2f(u16 h) { return __uint_as_float(((unsigned)h) << 16); }

// ---------------- xbar = mean over L of x ----------------
__global__ void k_xbar1(const float* __restrict__ x, float* __restrict__ part) {
    int t = threadIdx.x;
    int dblk = blockIdx.x, lc = blockIdx.y, b = blockIdx.z;
    int d = dblk*256 + t;
    const float* px = x + ((size_t)b*L_ + (size_t)lc*64)*D_ + d;
    float s = 0.f;
    #pragma unroll 4
    for (int l = 0; l < 64; ++l) s += px[(size_t)l*D_];
    part[(size_t)(b*32 + lc)*D_ + d] = s;
}

__global__ void k_xbar2(const float* __restrict__ part, float* __restrict__ xbar) {
    int id = blockIdx.x*256 + threadIdx.x;
    int b = id >> 10, d = id & 1023;
    float s = 0.f;
    for (int c = 0; c < 32; ++c) s += part[(size_t)(b*32 + c)*D_ + d];
    xbar[id] = s * (1.0f/(float)L_);
}

// ---------------- q_mean stage 1: qpart[kc][b][d] = sum_{k in chunk} xbar[b][k]*Wq[k][d] ----------------
__global__ void k_qmean1(const float* __restrict__ xbar, const float* __restrict__ Wq,
                         float* __restrict__ qpart) {
    int t = threadIdx.x;
    int dblk = blockIdx.x, b = blockIdx.y, kc = blockIdx.z;
    int d = dblk*256 + t;
    const float* xb = xbar + b*D_ + kc*128;
    const float* wq = Wq + (size_t)(kc*128)*D_ + d;
    float s = 0.f;
    #pragma unroll 8
    for (int k = 0; k < 128; ++k) s += xb[k] * wq[(size_t)k*D_];
    qpart[((size_t)kc*B_ + b)*D_ + d] = s;
}

// ---------------- gates part A: reduce qpart -> LN -> MLPs -> h1, wscale ----------------
__global__ void k_gates_a(const float* __restrict__ qpart,
                          const float* __restrict__ g_ln_w, const float* __restrict__ g_ln_b,
                          const float* __restrict__ g_w1,  const float* __restrict__ g_b1,
                          const float* __restrict__ w_ln_w, const float* __restrict__ w_ln_b,
                          const float* __restrict__ w_w1,  const float* __restrict__ w_b1,
                          const float* __restrict__ w_w2,  const float* __restrict__ w_b2,
                          float* __restrict__ h1_out, float* __restrict__ wscale) {
    int bh = blockIdx.x;
    int b = bh >> 4, h = bh & 15;
    int t = threadIdx.x;
    __shared__ float qm[64], hg[64], wh[64], w1o[64];

    if (t < 64) {
        float s = 0.f;
        #pragma unroll
        for (int kc = 0; kc < 8; ++kc)
            s += qpart[((size_t)kc*B_ + b)*D_ + h*64 + t];
        qm[t] = s;
    }
    __syncthreads();

    float m = 0.f;
    #pragma unroll
    for (int k = 0; k < 64; ++k) m += qm[k];
    m *= (1.0f/64.0f);
    float var = 0.f;
    #pragma unroll
    for (int k = 0; k < 64; ++k) { float df = qm[k]-m; var += df*df; }
    var *= (1.0f/64.0f);
    float rs = rsqrtf(var + 1e-5f);
    if (t < 64) {
        float c = (qm[t]-m)*rs;
        hg[t] = c*g_ln_w[t] + g_ln_b[t];
        wh[t] = c*w_ln_w[t] + w_ln_b[t];
    }
    __syncthreads();

    {
        float acc = g_b1[t];
        #pragma unroll 16
        for (int k = 0; k < 64; ++k) acc += hg[k]*g_w1[k*256 + t];
        h1_out[bh*256 + t] = 0.5f*acc*(1.0f + erff(acc*0.70710678118654752f));
    }
    if (t < 64) {
        float acc = w_b1[t];
        #pragma unroll 16
        for (int k = 0; k < 64; ++k) acc += wh[k]*w_w1[k*64 + t];
        w1o[t] = 0.5f*acc*(1.0f + erff(acc*0.70710678118654752f));
    }
    __syncthreads();

    if (t < 64) {
        float acc = w_b2[t];
        #pragma unroll 16
        for (int k = 0; k < 64; ++k) acc += w1o[k]*w_w2[k*64 + t];
        wscale[bh*64 + t] = 1.0f + 1.0f/(1.0f + expf(-acc));
    }
}

// ---------------- gates part B: G = herm-extend(modulate(h1 @ g_w2 + g_b2)) ----------------
__global__ __launch_bounds__(256) void k_gate_g(const float* __restrict__ h1_ws,
                                                const float* __restrict__ g_w2,
                                                const float* __restrict__ g_b2,
                                                const float* __restrict__ mod_bias,
                                                float* __restrict__ G) {
    int bh = blockIdx.y;
    int f = blockIdx.x*256 + threadIdx.x;
    __shared__ float h1[256];
    h1[threadIdx.x] = h1_ws[bh*256 + threadIdx.x];
    __syncthreads();
    if (f >= NF) return;

    float re = g_b2[f], im = g_b2[NF + f];
    #pragma unroll 4
    for (int k = 0; k < 256; ++k) {
        float hv = h1[k];
        re += hv*g_w2[(size_t)k*2050 + f];
        im += hv*g_w2[(size_t)k*2050 + NF + f];
    }
    float mag = sqrtf(re*re + im*im);
    float mult = fmaxf(mag + mod_bias[f], 0.f) / (mag + 1e-6f);
    float s = mult * (1.0f/2048.0f);
    float gr = s*re, gi = s*im;
    if (f == 0 || f == 1024) gi = 0.f;
    float* Gb = G + (size_t)bh*4096;
    Gb[2*f]   = gr;
    Gb[2*f+1] = gi;
    if (f >= 1 && f <= 1023) {
        Gb[2*(2048-f)]   = gr;
        Gb[2*(2048-f)+1] = -gi;
    }
}

// ---------------- x -> bf16 hi/lo split ----------------
__global__ void k_xsplit(const float4* __restrict__ x, u16* __restrict__ hi, u16* __restrict__ lo) {
    int i = blockIdx.x*256 + threadIdx.x;
    float4 v = x[i];
    ushort4 h, l;
    h.x = f2bf(v.x); l.x = f2bf(v.x - bf2f(h.x));
    h.y = f2bf(v.y); l.y = f2bf(v.y - bf2f(h.y));
    h.z = f2bf(v.z); l.z = f2bf(v.z - bf2f(h.z));
    h.w = f2bf(v.w); l.w = f2bf(v.w - bf2f(h.w));
    ((ushort4*)hi)[i] = h;
    ((ushort4*)lo)[i] = l;
}

// ---------------- weight transpose + bf16 hi/lo split : W[k][n] -> Wt[n][k] ----------------
__global__ void k_wsplit(const float* __restrict__ Wv, const float* __restrict__ Wo,
                         u16* __restrict__ WvH, u16* __restrict__ WvL,
                         u16* __restrict__ WoH, u16* __restrict__ WoL) {
    const float* W = blockIdx.z ? Wo : Wv;
    u16* TH = blockIdx.z ? WoH : WvH;
    u16* TL = blockIdx.z ? WoL : WvL;
    __shared__ float tile[32][33];
    int t = threadIdx.x;
    int n0 = blockIdx.x*32, k0 = blockIdx.y*32;
    #pragma unroll
    for (int i = 0; i < 4; ++i) {
        int k = (t >> 5) + 8*i;
        tile[k][t & 31] = W[(size_t)(k0 + k)*D_ + n0 + (t & 31)];
    }
    __syncthreads();
    int n = t >> 3, kc = (t & 7)*4;
    float f0 = tile[kc+0][n], f1 = tile[kc+1][n], f2 = tile[kc+2][n], f3 = tile[kc+3][n];
    ushort4 h, l;
    h.x = f2bf(f0); l.x = f2bf(f0 - bf2f(h.x));
    h.y = f2bf(f1); l.y = f2bf(f1 - bf2f(h.y));
    h.z = f2bf(f2); l.z = f2bf(f2 - bf2f(h.z));
    h.w = f2bf(f3); l.w = f2bf(f3 - bf2f(h.w));
    *(ushort4*)&TH[(size_t)(n0 + n)*D_ + k0 + kc] = h;
    *(ushort4*)&TL[(size_t)(n0 + n)*D_ + k0 + kc] = l;
}

// ---------------- bf16x3 MFMA GEMM ----------------
__device__ __forceinline__ void gemm_seg(const u16* __restrict__ Ag, const u16* __restrict__ Bg,
                                         u16* As, u16* Bs, f32x4 (&acc)[4][4],
                                         size_t rowBase, int colBase, int t) {
    int lane = t & 63;
    int wr = (t >> 7) & 1, wc = (t >> 6) & 1;
    int lr = lane & 15, lk = (lane >> 4) << 3;
    for (int k0 = 0; k0 < 1024; k0 += 64) {
        #pragma unroll
        for (int i = 0; i < 4; ++i) {
            int c = t + i*256;
            int r = c >> 3, ko = (c & 7) << 3;
            __builtin_amdgcn_global_load_lds(
                (const __attribute__((address_space(1))) void*)(Ag + (rowBase + (size_t)r)*D_ + k0 + ko),
                (__attribute__((address_space(3))) void*)(As + c*8), 16, 0, 0);
        }
        #pragma unroll
        for (int i = 0; i < 4; ++i) {
            int c = t + i*256;
            int r = c >> 3, ko = (c & 7) << 3;
            __builtin_amdgcn_global_load_lds(
                (const __attribute__((address_space(1))) void*)(Bg + ((size_t)colBase + r)*D_ + k0 + ko),
                (__attribute__((address_space(3))) void*)(Bs + c*8), 16, 0, 0);
        }
        __syncthreads();
        #pragma unroll
        for (int ks = 0; ks < 2; ++ks) {
            bf16x8 a[4], b[4];
            #pragma unroll
            for (int m = 0; m < 4; ++m)
                a[m] = *(const bf16x8*)(As + (wr*64 + m*16 + lr)*64 + ks*32 + lk);
            #pragma unroll
            for (int n = 0; n < 4; ++n)
                b[n] = *(const bf16x8*)(Bs + (wc*64 + n*16 + lr)*64 + ks*32 + lk);
            #pragma unroll
            for (int m = 0; m < 4; ++m) {
                #pragma unroll
                for (int n = 0; n < 4; ++n)
                    acc[m][n] = __builtin_amdgcn_mfma_f32_16x16x32_bf16(a[m], b[n], acc[m][n], 0, 0, 0);
            }
        }
        __syncthreads();
    }
}

template<int EPI>
__global__ void k_mfma_gemm(const u16* __restrict__ A0, const u16* __restrict__ A1, const u16* __restrict__ A2,
                            const u16* __restrict__ B0, const u16* __restrict__ B1, const u16* __restrict__ B2,
                            float* __restrict__ C) {
    __shared__ u16 As[128*64];
    __shared__ u16 Bs[128*64];
    int t = threadIdx.x;
    size_t rowBase = (size_t)blockIdx.x * 128;
    int colBase = blockIdx.y * 128;
    f32x4 acc[4][4] = {};

    gemm_seg(A0, B0, As, Bs, acc, rowBase, colBase, t);
    gemm_seg(A1, B1, As, Bs, acc, rowBase, colBase, t);
    gemm_seg(A2, B2, As, Bs, acc, rowBase, colBase, t);

    int lane = t & 63;
    int wr = (t >> 7) & 1, wc = (t >> 6) & 1;
    int cr = (lane >> 4) * 4, cc = lane & 15;
    if (EPI == 0) {
        #pragma unroll
        for (int m = 0; m < 4; ++m) {
            #pragma unroll
            for (int n = 0; n < 4; ++n) {
                int d = colBase + wc*64 + n*16 + cc;
                int hh = d >> 6, pr = (d >> 1) & 31, p = d & 1;
                #pragma unroll
                for (int r = 0; r < 4; ++r) {
                    size_t gr = rowBase + wr*64 + m*16 + cr + r;
                    int b = (int)(gr >> 11), l = (int)(gr & 2047);
                    C[(((size_t)((b*16 + hh)*32 + pr))*L_ + l)*2 + p] = acc[m][n][r];
                }
            }
        }
    } else {
        #pragma unroll
        for (int m = 0; m < 4; ++m) {
            #pragma unroll
            for (int n = 0; n < 4; ++n) {
                int d = colBase + wc*64 + n*16 + cc;
                #pragma unroll
                for (int r = 0; r < 4; ++r) {
                    size_t gr = rowBase + wr*64 + m*16 + cr + r;
                    C[gr*D_ + d] = acc[m][n][r];
                }
            }
        }
    }
}

// ---------------- packed complex FFT-2048 ----------------
__global__ __launch_bounds__(256) void k_fft(float* __restrict__ z,
                                             const float* __restrict__ G,
                                             const float* __restrict__ wscale) {
    __shared__ float re[2048], im[2048];
    __shared__ float twr[1024], twi[1024];
    int t = threadIdx.x;
    int row = blockIdx.x;
    int bh = row >> 5, j = row & 31;
    float2* zr = (float2*)z + (size_t)row * L_;

    #pragma unroll
    for (int k = 0; k < 8; ++k) {
        int i = t + k*256;
        float2 v = zr[i];
        re[i] = v.x; im[i] = v.y;
    }
    #pragma unroll
    for (int k = 0; k < 4; ++k) {
        int i = t + k*256;
        float ang = -6.283185307179586f * (float)i / 2048.0f;
        float s, c;
        sincosf(ang, &s, &c);
        twr[i] = c; twi[i] = s;
    }
    __syncthreads();

    for (int len = 1024; len >= 1; len >>= 1) {
        int step = 1024 / len;
        #pragma unroll
        for (int k = 0; k < 4; ++k) {
            int idx = t + k*256;
            int off = idx & (len-1);
            int i0 = ((idx - off) << 1) + off;
            int i1 = i0 + len;
            float ar = re[i0], ai = im[i0], br = re[i1], bi = im[i1];
            re[i0] = ar + br; im[i0] = ai + bi;
            float tr = ar - br, ti = ai - bi;
            int w = off * step;
            float wr_ = twr[w], wim = twi[w];
            re[i1] = tr*wr_ - ti*wim;
            im[i1] = tr*wim + ti*wr_;
        }
        __syncthreads();
    }

    const float* Gb = G + (size_t)bh * 4096;
    #pragma unroll
    for (int k = 0; k < 8; ++k) {
        int p = t + k*256;
        int f = (int)(__brev((unsigned)p) >> 21);
        float gr = Gb[2*f], gi = Gb[2*f+1];
        float xr = re[p], xi = im[p];
        re[p] = xr*gr - xi*gi;
        im[p] = xr*gi + xi*gr;
    }
    __syncthreads();

    for (int len = 1; len <= 1024; len <<= 1) {
        int step = 1024 / len;
        #pragma unroll
        for (int k = 0; k < 4; ++k) {
            int idx = t + k*256;
            int off = idx & (len-1);
            int i0 = ((idx - off) << 1) + off;
            int i1 = i0 + len;
            int w = off * step;
            float wr_ = twr[w], wim = -twi[w];
            float br = re[i1], bi = im[i1];
            float tr = br*wr_ - bi*wim;
            float ti = br*wim + bi*wr_;
            float ar = re[i0], ai = im[i0];
            re[i0] = ar + tr; im[i0] = ai + ti;
            re[i1] = ar - tr; im[i1] = ai - ti;
        }
        __syncthreads();
    }

    float sc0 = wscale[bh*64 + 2*j];
    float sc1 = wscale[bh*64 + 2*j + 1];
    #pragma unroll
    for (int k = 0; k < 8; ++k) {
        int i = t + k*256;
        zr[i] = make_float2(re[i]*sc0, im[i]*sc1);
    }
}

// ---------------- z (fp32, packed layout) -> vmix [m][d] bf16 hi/lo ----------------
__global__ void k_vsplit(const float* __restrict__ z, u16* __restrict__ vhi, u16* __restrict__ vlo) {
    int t = threadIdx.x;
    int lt = blockIdx.x, h = blockIdx.y, b = blockIdx.z;
    int l0 = lt*64;
    __shared__ float tile[64][65];
    const float2* zb = (const float2*)z + (size_t)(b*16 + h)*32*L_;
    int pr = t >> 3, lg = t & 7;
    #pragma unroll
    for (int i = 0; i < 8; ++i) {
        int l = lg*8 + i;
        float2 v = zb[(size_t)pr*L_ + l0 + l];
        tile[l][2*pr]   = v.x;
        tile[l][2*pr+1] = v.y;
    }
    __syncthreads();
    int l = t >> 2, d0 = (t & 3) * 16;
    u16x8 h0, h1v, l0v, l1v;
    #pragma unroll
    for (int i = 0; i < 8; ++i) {
        float f = tile[l][d0+i];
        u16 hb = f2bf(f);
        h0[i] = hb; l0v[i] = f2bf(f - bf2f(hb));
    }
    #pragma unroll
    for (int i = 0; i < 8; ++i) {
        float f = tile[l][d0+8+i];
        u16 hb = f2bf(f);
        h1v[i] = hb; l1v[i] = f2bf(f - bf2f(hb));
    }
    size_t base = ((size_t)(b*L_) + l0 + l)*D_ + h*64 + d0;
    *(u16x8*)&vhi[base]   = h0;
    *(u16x8*)&vhi[base+8] = h1v;
    *(u16x8*)&vlo[base]   = l0v;
    *(u16x8*)&vlo[base+8] = l1v;
}

extern "C" void kernel_launch(void* const* d_in, const int* in_sizes, int n_in,
                              void* d_out, int out_size, void* d_ws, size_t ws_size,
                              hipStream_t stream) {
    const float* x      = (const float*)d_in[0];
    const float* Wq     = (const float*)d_in[1];
    const float* Wv     = (const float*)d_in[2];
    const float* Wo     = (const float*)d_in[3];
    const float* g_ln_w = (const float*)d_in[4];
    const float* g_ln_b = (const float*)d_in[5];
    const float* g_w1   = (const float*)d_in[6];
    const float* g_b1   = (const float*)d_in[7];
    const float* g_w2   = (const float*)d_in[8];
    const float* g_b2   = (const float*)d_in[9];
    const float* mod_b  = (const float*)d_in[10];
    const float* w_ln_w = (const float*)d_in[11];
    const float* w_ln_b = (const float*)d_in[12];
    const float* w_w1   = (const float*)d_in[13];
    const float* w_b1   = (const float*)d_in[14];
    const float* w_w2   = (const float*)d_in[15];
    const float* w_b2   = (const float*)d_in[16];

    float* ws   = (float*)d_ws;
    float* z    = ws + Z_OFF;
    float* G    = ws + G_OFF;
    float* wsc  = ws + WSC_OFF;
    float* xbar = ws + XB_OFF;
    float* part = ws + PART_OFF;
    float* h1ws = ws + H1_OFF;
    float* qpart= ws + QP_OFF;
    u16* xhi = (u16*)(ws + XHI_OFF);
    u16* xlo = (u16*)(ws + XLO_OFF);
    u16* WvH = (u16*)(ws + WVH_OFF);
    u16* WvL = (u16*)(ws + WVL_OFF);
    u16* WoH = (u16*)(ws + WOH_OFF);
    u16* WoL = (u16*)(ws + WOL_OFF);
    u16* vhi = xhi;
    u16* vlo = xlo;
    float* outp = (float*)d_out;

    dim3 gx(4, 32, 4);
    k_xbar1<<<gx, 256, 0, stream>>>(x, part);
    k_xbar2<<<16, 256, 0, stream>>>(part, xbar);
    dim3 gq(4, 4, 8);
    k_qmean1<<<gq, 256, 0, stream>>>(xbar, Wq, qpart);
    k_gates_a<<<64, 256, 0, stream>>>(qpart, g_ln_w, g_ln_b, g_w1, g_b1,
                                      w_ln_w, w_ln_b, w_w1, w_b1, w_w2, w_b2,
                                      h1ws, wsc);
    dim3 ggate(5, 64);
    k_gate_g<<<ggate, 256, 0, stream>>>(h1ws, g_w2, g_b2, mod_b, G);
    k_xsplit<<<8192, 256, 0, stream>>>((const float4*)x, xhi, xlo);
    dim3 gw(32, 32, 2);
    k_wsplit<<<gw, 256, 0, stream>>>(Wv, Wo, WvH, WvL, WoH, WoL);

    dim3 gg(64, 8);
    k_mfma_gemm<0><<<gg, 256, 0, stream>>>(xhi, xhi, xlo, WvH, WvL, WvH, z);
    k_fft<<<2048, 256, 0, stream>>>(z, G, wsc);
    dim3 gv(32, 16, 4);
    k_vsplit<<<gv, 256, 0, stream>>>(z, vhi, vlo);
    k_mfma_gemm<1><<<gg, 256, 0, stream>>>(vhi, vhi, vlo, WoH, WoL, WoH, outp);
}

// Round 5
// 261.113 us; speedup vs baseline: 3.8702x; 1.2367x over previous
//
#include <hip/hip_runtime.h>
#include <math.h>

typedef unsigned short u16;
typedef short bf16x8 __attribute__((ext_vector_type(8)));
typedef float f32x4 __attribute__((ext_vector_type(4)));
typedef u16 u16x8 __attribute__((ext_vector_type(8)));

#define B_ 4
#define L_ 2048
#define D_ 1024
#define H_ 16
#define DH 64
#define NF 1025
#define BH (B_*H_)

// ---- workspace layout (in floats) ----
#define Z_OFF    0
#define G_OFF    8388608
#define WSC_OFF  (G_OFF + 262144)
#define XB_OFF   (WSC_OFF + 4096)
#define PART_OFF (XB_OFF + 4096)
#define H1_OFF   (PART_OFF + 131072)
#define QP_OFF   (H1_OFF + 16384)
#define XHI_OFF  (QP_OFF + 32768)
#define XLO_OFF  (XHI_OFF + 4194304)
#define WVH_OFF  (XLO_OFF + 4194304)
#define WVL_OFF  (WVH_OFF + 524288)
#define WOH_OFF  (WVL_OFF + 524288)
#define WOL_OFF  (WOH_OFF + 524288)

__device__ __forceinline__ u16 f2bf(float f) {
    unsigned u = __float_as_uint(f);
    unsigned r = u + 0x7FFFu + ((u >> 16) & 1u);
    return (u16)(r >> 16);
}
__device__ __forceinline__ float bf2f(u16 h) { return __uint_as_float(((unsigned)h) << 16); }

// ---------------- xbar = mean over L of x ----------------
__global__ void k_xbar1(const float* __restrict__ x, float* __restrict__ part) {
    int t = threadIdx.x;
    int dblk = blockIdx.x, lc = blockIdx.y, b = blockIdx.z;
    int d = dblk*256 + t;
    const float* px = x + ((size_t)b*L_ + (size_t)lc*64)*D_ + d;
    float s = 0.f;
    #pragma unroll 4
    for (int l = 0; l < 64; ++l) s += px[(size_t)l*D_];
    part[(size_t)(b*32 + lc)*D_ + d] = s;
}

__global__ void k_xbar2(const float* __restrict__ part, float* __restrict__ xbar) {
    int id = blockIdx.x*256 + threadIdx.x;
    int b = id >> 10, d = id & 1023;
    float s = 0.f;
    for (int c = 0; c < 32; ++c) s += part[(size_t)(b*32 + c)*D_ + d];
    xbar[id] = s * (1.0f/(float)L_);
}

// ---------------- q_mean stage 1 ----------------
__global__ void k_qmean1(const float* __restrict__ xbar, const float* __restrict__ Wq,
                         float* __restrict__ qpart) {
    int t = threadIdx.x;
    int dblk = blockIdx.x, b = blockIdx.y, kc = blockIdx.z;
    int d = dblk*256 + t;
    const float* xb = xbar + b*D_ + kc*128;
    const float* wq = Wq + (size_t)(kc*128)*D_ + d;
    float s = 0.f;
    #pragma unroll 8
    for (int k = 0; k < 128; ++k) s += xb[k] * wq[(size_t)k*D_];
    qpart[((size_t)kc*B_ + b)*D_ + d] = s;
}

// ---------------- gates part A ----------------
__global__ void k_gates_a(const float* __restrict__ qpart,
                          const float* __restrict__ g_ln_w, const float* __restrict__ g_ln_b,
                          const float* __restrict__ g_w1,  const float* __restrict__ g_b1,
                          const float* __restrict__ w_ln_w, const float* __restrict__ w_ln_b,
                          const float* __restrict__ w_w1,  const float* __restrict__ w_b1,
                          const float* __restrict__ w_w2,  const float* __restrict__ w_b2,
                          float* __restrict__ h1_out, float* __restrict__ wscale) {
    int bh = blockIdx.x;
    int b = bh >> 4, h = bh & 15;
    int t = threadIdx.x;
    __shared__ float qm[64], hg[64], wh[64], w1o[64];

    if (t < 64) {
        float s = 0.f;
        #pragma unroll
        for (int kc = 0; kc < 8; ++kc)
            s += qpart[((size_t)kc*B_ + b)*D_ + h*64 + t];
        qm[t] = s;
    }
    __syncthreads();

    float m = 0.f;
    #pragma unroll
    for (int k = 0; k < 64; ++k) m += qm[k];
    m *= (1.0f/64.0f);
    float var = 0.f;
    #pragma unroll
    for (int k = 0; k < 64; ++k) { float df = qm[k]-m; var += df*df; }
    var *= (1.0f/64.0f);
    float rs = rsqrtf(var + 1e-5f);
    if (t < 64) {
        float c = (qm[t]-m)*rs;
        hg[t] = c*g_ln_w[t] + g_ln_b[t];
        wh[t] = c*w_ln_w[t] + w_ln_b[t];
    }
    __syncthreads();

    {
        float acc = g_b1[t];
        #pragma unroll 16
        for (int k = 0; k < 64; ++k) acc += hg[k]*g_w1[k*256 + t];
        h1_out[bh*256 + t] = 0.5f*acc*(1.0f + erff(acc*0.70710678118654752f));
    }
    if (t < 64) {
        float acc = w_b1[t];
        #pragma unroll 16
        for (int k = 0; k < 64; ++k) acc += wh[k]*w_w1[k*64 + t];
        w1o[t] = 0.5f*acc*(1.0f + erff(acc*0.70710678118654752f));
    }
    __syncthreads();

    if (t < 64) {
        float acc = w_b2[t];
        #pragma unroll 16
        for (int k = 0; k < 64; ++k) acc += w1o[k]*w_w2[k*64 + t];
        wscale[bh*64 + t] = 1.0f + 1.0f/(1.0f + expf(-acc));
    }
}

// ---------------- gates part B ----------------
__global__ __launch_bounds__(256) void k_gate_g(const float* __restrict__ h1_ws,
                                                const float* __restrict__ g_w2,
                                                const float* __restrict__ g_b2,
                                                const float* __restrict__ mod_bias,
                                                float* __restrict__ G) {
    int bh = blockIdx.y;
    int f = blockIdx.x*256 + threadIdx.x;
    __shared__ float h1[256];
    h1[threadIdx.x] = h1_ws[bh*256 + threadIdx.x];
    __syncthreads();
    if (f >= NF) return;

    float re = g_b2[f], im = g_b2[NF + f];
    #pragma unroll 4
    for (int k = 0; k < 256; ++k) {
        float hv = h1[k];
        re += hv*g_w2[(size_t)k*2050 + f];
        im += hv*g_w2[(size_t)k*2050 + NF + f];
    }
    float mag = sqrtf(re*re + im*im);
    float mult = fmaxf(mag + mod_bias[f], 0.f) / (mag + 1e-6f);
    float s = mult * (1.0f/2048.0f);
    float gr = s*re, gi = s*im;
    if (f == 0 || f == 1024) gi = 0.f;
    float* Gb = G + (size_t)bh*4096;
    Gb[2*f]   = gr;
    Gb[2*f+1] = gi;
    if (f >= 1 && f <= 1023) {
        Gb[2*(2048-f)]   = gr;
        Gb[2*(2048-f)+1] = -gi;
    }
}

// ---------------- x -> bf16 hi/lo split ----------------
__global__ void k_xsplit(const float4* __restrict__ x, u16* __restrict__ hi, u16* __restrict__ lo) {
    int i = blockIdx.x*256 + threadIdx.x;
    float4 v = x[i];
    ushort4 h, l;
    h.x = f2bf(v.x); l.x = f2bf(v.x - bf2f(h.x));
    h.y = f2bf(v.y); l.y = f2bf(v.y - bf2f(h.y));
    h.z = f2bf(v.z); l.z = f2bf(v.z - bf2f(h.z));
    h.w = f2bf(v.w); l.w = f2bf(v.w - bf2f(h.w));
    ((ushort4*)hi)[i] = h;
    ((ushort4*)lo)[i] = l;
}

// ---------------- weight transpose + bf16 hi/lo split ----------------
__global__ void k_wsplit(const float* __restrict__ Wv, const float* __restrict__ Wo,
                         u16* __restrict__ WvH, u16* __restrict__ WvL,
                         u16* __restrict__ WoH, u16* __restrict__ WoL) {
    const float* W = blockIdx.z ? Wo : Wv;
    u16* TH = blockIdx.z ? WoH : WvH;
    u16* TL = blockIdx.z ? WoL : WvL;
    __shared__ float tile[32][33];
    int t = threadIdx.x;
    int n0 = blockIdx.x*32, k0 = blockIdx.y*32;
    #pragma unroll
    for (int i = 0; i < 4; ++i) {
        int k = (t >> 5) + 8*i;
        tile[k][t & 31] = W[(size_t)(k0 + k)*D_ + n0 + (t & 31)];
    }
    __syncthreads();
    int n = t >> 3, kc = (t & 7)*4;
    float f0 = tile[kc+0][n], f1 = tile[kc+1][n], f2 = tile[kc+2][n], f3 = tile[kc+3][n];
    ushort4 h, l;
    h.x = f2bf(f0); l.x = f2bf(f0 - bf2f(h.x));
    h.y = f2bf(f1); l.y = f2bf(f1 - bf2f(h.y));
    h.z = f2bf(f2); l.z = f2bf(f2 - bf2f(h.z));
    h.w = f2bf(f3); l.w = f2bf(f3 - bf2f(h.w));
    *(ushort4*)&TH[(size_t)(n0 + n)*D_ + k0 + kc] = h;
    *(ushort4*)&TL[(size_t)(n0 + n)*D_ + k0 + kc] = l;
}

// ---------------- fused bf16x3 MFMA GEMM with XOR-swizzled LDS ----------------
// LDS tile: [128 rows][64 u16] linear; chunk = 16B. Staged with pre-swizzled
// global source (chunk cs holds global chunk cs^(r&7)); reads XOR the same way.
__device__ __forceinline__ void stage4(const u16* __restrict__ gbase, u16* lds, int t) {
    #pragma unroll
    for (int i = 0; i < 4; ++i) {
        int c = t + i*256;
        int r = c >> 3, cs = c & 7;
        int ko = (cs ^ (r & 7)) << 3;
        __builtin_amdgcn_global_load_lds(
            (const __attribute__((address_space(1))) void*)(gbase + (size_t)r*D_ + ko),
            (__attribute__((address_space(3))) void*)(lds + c*8), 16, 0, 0);
    }
}

template<int EPI>
__global__ __launch_bounds__(256) void k_mfma_gemm(const u16* __restrict__ Ahi, const u16* __restrict__ Alo,
                                                   const u16* __restrict__ Bhi, const u16* __restrict__ Blo,
                                                   float* __restrict__ C) {
    __shared__ u16 AsH[128*64], AsL[128*64], BsH[128*64], BsL[128*64];
    int t = threadIdx.x;
    size_t rowBase = (size_t)blockIdx.x * 128;
    int colBase = blockIdx.y * 128;
    f32x4 acc[4][4] = {};
    int lane = t & 63;
    int wr = (t >> 7) & 1, wc = (t >> 6) & 1;
    int lr = lane & 15, lq = lane >> 4;

    for (int k0 = 0; k0 < 1024; k0 += 64) {
        stage4(Ahi + rowBase*D_ + k0, AsH, t);
        stage4(Alo + rowBase*D_ + k0, AsL, t);
        stage4(Bhi + (size_t)colBase*D_ + k0, BsH, t);
        stage4(Blo + (size_t)colBase*D_ + k0, BsL, t);
        __syncthreads();
        #pragma unroll
        for (int ks = 0; ks < 2; ++ks) {
            bf16x8 ah[4], al[4], bh[4], bl[4];
            #pragma unroll
            for (int m = 0; m < 4; ++m) {
                int row = wr*64 + m*16 + lr;
                int ch = (ks*4 + lq) ^ (row & 7);
                ah[m] = *(const bf16x8*)(AsH + row*64 + ch*8);
                al[m] = *(const bf16x8*)(AsL + row*64 + ch*8);
            }
            #pragma unroll
            for (int n = 0; n < 4; ++n) {
                int row = wc*64 + n*16 + lr;
                int ch = (ks*4 + lq) ^ (row & 7);
                bh[n] = *(const bf16x8*)(BsH + row*64 + ch*8);
                bl[n] = *(const bf16x8*)(BsL + row*64 + ch*8);
            }
            #pragma unroll
            for (int m = 0; m < 4; ++m) {
                #pragma unroll
                for (int n = 0; n < 4; ++n) {
                    acc[m][n] = __builtin_amdgcn_mfma_f32_16x16x32_bf16(ah[m], bh[n], acc[m][n], 0, 0, 0);
                    acc[m][n] = __builtin_amdgcn_mfma_f32_16x16x32_bf16(ah[m], bl[n], acc[m][n], 0, 0, 0);
                    acc[m][n] = __builtin_amdgcn_mfma_f32_16x16x32_bf16(al[m], bh[n], acc[m][n], 0, 0, 0);
                }
            }
        }
        __syncthreads();
    }

    int cr = lq * 4, cc = lane & 15;
    if (EPI == 0) {
        #pragma unroll
        for (int m = 0; m < 4; ++m) {
            #pragma unroll
            for (int n = 0; n < 4; ++n) {
                int d = colBase + wc*64 + n*16 + cc;
                int hh = d >> 6, pr = (d >> 1) & 31, p = d & 1;
                #pragma unroll
                for (int r = 0; r < 4; ++r) {
                    size_t gr = rowBase + wr*64 + m*16 + cr + r;
                    int b = (int)(gr >> 11), l = (int)(gr & 2047);
                    C[(((size_t)((b*16 + hh)*32 + pr))*L_ + l)*2 + p] = acc[m][n][r];
                }
            }
        }
    } else {
        #pragma unroll
        for (int m = 0; m < 4; ++m) {
            #pragma unroll
            for (int n = 0; n < 4; ++n) {
                int d = colBase + wc*64 + n*16 + cc;
                #pragma unroll
                for (int r = 0; r < 4; ++r) {
                    size_t gr = rowBase + wr*64 + m*16 + cr + r;
                    C[gr*D_ + d] = acc[m][n][r];
                }
            }
        }
    }
}

// ---------------- packed complex FFT-2048 ----------------
__global__ __launch_bounds__(256) void k_fft(float* __restrict__ z,
                                             const float* __restrict__ G,
                                             const float* __restrict__ wscale) {
    __shared__ float re[2048], im[2048];
    __shared__ float twr[1024], twi[1024];
    int t = threadIdx.x;
    int row = blockIdx.x;
    int bh = row >> 5, j = row & 31;
    float2* zr = (float2*)z + (size_t)row * L_;

    #pragma unroll
    for (int k = 0; k < 8; ++k) {
        int i = t + k*256;
        float2 v = zr[i];
        re[i] = v.x; im[i] = v.y;
    }
    #pragma unroll
    for (int k = 0; k < 4; ++k) {
        int i = t + k*256;
        float ang = -6.283185307179586f * (float)i / 2048.0f;
        float s, c;
        sincosf(ang, &s, &c);
        twr[i] = c; twi[i] = s;
    }
    __syncthreads();

    for (int len = 1024; len >= 1; len >>= 1) {
        int step = 1024 / len;
        #pragma unroll
        for (int k = 0; k < 4; ++k) {
            int idx = t + k*256;
            int off = idx & (len-1);
            int i0 = ((idx - off) << 1) + off;
            int i1 = i0 + len;
            float ar = re[i0], ai = im[i0], br = re[i1], bi = im[i1];
            re[i0] = ar + br; im[i0] = ai + bi;
            float tr = ar - br, ti = ai - bi;
            int w = off * step;
            float wr_ = twr[w], wim = twi[w];
            re[i1] = tr*wr_ - ti*wim;
            im[i1] = tr*wim + ti*wr_;
        }
        __syncthreads();
    }

    const float* Gb = G + (size_t)bh * 4096;
    #pragma unroll
    for (int k = 0; k < 8; ++k) {
        int p = t + k*256;
        int f = (int)(__brev((unsigned)p) >> 21);
        float gr = Gb[2*f], gi = Gb[2*f+1];
        float xr = re[p], xi = im[p];
        re[p] = xr*gr - xi*gi;
        im[p] = xr*gi + xi*gr;
    }
    __syncthreads();

    for (int len = 1; len <= 1024; len <<= 1) {
        int step = 1024 / len;
        #pragma unroll
        for (int k = 0; k < 4; ++k) {
            int idx = t + k*256;
            int off = idx & (len-1);
            int i0 = ((idx - off) << 1) + off;
            int i1 = i0 + len;
            int w = off * step;
            float wr_ = twr[w], wim = -twi[w];
            float br = re[i1], bi = im[i1];
            float tr = br*wr_ - bi*wim;
            float ti = br*wim + bi*wr_;
            float ar = re[i0], ai = im[i0];
            re[i0] = ar + tr; im[i0] = ai + ti;
            re[i1] = ar - tr; im[i1] = ai - ti;
        }
        __syncthreads();
    }

    float sc0 = wscale[bh*64 + 2*j];
    float sc1 = wscale[bh*64 + 2*j + 1];
    #pragma unroll
    for (int k = 0; k < 8; ++k) {
        int i = t + k*256;
        zr[i] = make_float2(re[i]*sc0, im[i]*sc1);
    }
}

// ---------------- z -> vmix [m][d] bf16 hi/lo ----------------
__global__ void k_vsplit(const float* __restrict__ z, u16* __restrict__ vhi, u16* __restrict__ vlo) {
    int t = threadIdx.x;
    int lt = blockIdx.x, h = blockIdx.y, b = blockIdx.z;
    int l0 = lt*64;
    __shared__ float tile[64][65];
    const float2* zb = (const float2*)z + (size_t)(b*16 + h)*32*L_;
    int pr = t >> 3, lg = t & 7;
    #pragma unroll
    for (int i = 0; i < 8; ++i) {
        int l = lg*8 + i;
        float2 v = zb[(size_t)pr*L_ + l0 + l];
        tile[l][2*pr]   = v.x;
        tile[l][2*pr+1] = v.y;
    }
    __syncthreads();
    int l = t >> 2, d0 = (t & 3) * 16;
    u16x8 h0, h1v, l0v, l1v;
    #pragma unroll
    for (int i = 0; i < 8; ++i) {
        float f = tile[l][d0+i];
        u16 hb = f2bf(f);
        h0[i] = hb; l0v[i] = f2bf(f - bf2f(hb));
    }
    #pragma unroll
    for (int i = 0; i < 8; ++i) {
        float f = tile[l][d0+8+i];
        u16 hb = f2bf(f);
        h1v[i] = hb; l1v[i] = f2bf(f - bf2f(hb));
    }
    size_t base = ((size_t)(b*L_) + l0 + l)*D_ + h*64 + d0;
    *(u16x8*)&vhi[base]   = h0;
    *(u16x8*)&vhi[base+8] = h1v;
    *(u16x8*)&vlo[base]   = l0v;
    *(u16x8*)&vlo[base+8] = l1v;
}

extern "C" void kernel_launch(void* const* d_in, const int* in_sizes, int n_in,
                              void* d_out, int out_size, void* d_ws, size_t ws_size,
                              hipStream_t stream) {
    const float* x      = (const float*)d_in[0];
    const float* Wq     = (const float*)d_in[1];
    const float* Wv     = (const float*)d_in[2];
    const float* Wo     = (const float*)d_in[3];
    const float* g_ln_w = (const float*)d_in[4];
    const float* g_ln_b = (const float*)d_in[5];
    const float* g_w1   = (const float*)d_in[6];
    const float* g_b1   = (const float*)d_in[7];
    const float* g_w2   = (const float*)d_in[8];
    const float* g_b2   = (const float*)d_in[9];
    const float* mod_b  = (const float*)d_in[10];
    const float* w_ln_w = (const float*)d_in[11];
    const float* w_ln_b = (const float*)d_in[12];
    const float* w_w1   = (const float*)d_in[13];
    const float* w_b1   = (const float*)d_in[14];
    const float* w_w2   = (const float*)d_in[15];
    const float* w_b2   = (const float*)d_in[16];

    float* ws   = (float*)d_ws;
    float* z    = ws + Z_OFF;
    float* G    = ws + G_OFF;
    float* wsc  = ws + WSC_OFF;
    float* xbar = ws + XB_OFF;
    float* part = ws + PART_OFF;
    float* h1ws = ws + H1_OFF;
    float* qpart= ws + QP_OFF;
    u16* xhi = (u16*)(ws + XHI_OFF);
    u16* xlo = (u16*)(ws + XLO_OFF);
    u16* WvH = (u16*)(ws + WVH_OFF);
    u16* WvL = (u16*)(ws + WVL_OFF);
    u16* WoH = (u16*)(ws + WOH_OFF);
    u16* WoL = (u16*)(ws + WOL_OFF);
    u16* vhi = xhi;
    u16* vlo = xlo;
    float* outp = (float*)d_out;

    dim3 gx(4, 32, 4);
    k_xbar1<<<gx, 256, 0, stream>>>(x, part);
    k_xbar2<<<16, 256, 0, stream>>>(part, xbar);
    dim3 gq(4, 4, 8);
    k_qmean1<<<gq, 256, 0, stream>>>(xbar, Wq, qpart);
    k_gates_a<<<64, 256, 0, stream>>>(qpart, g_ln_w, g_ln_b, g_w1, g_b1,
                                      w_ln_w, w_ln_b, w_w1, w_b1, w_w2, w_b2,
                                      h1ws, wsc);
    dim3 ggate(5, 64);
    k_gate_g<<<ggate, 256, 0, stream>>>(h1ws, g_w2, g_b2, mod_b, G);
    k_xsplit<<<8192, 256, 0, stream>>>((const float4*)x, xhi, xlo);
    dim3 gw(32, 32, 2);
    k_wsplit<<<gw, 256, 0, stream>>>(Wv, Wo, WvH, WvL, WoH, WoL);

    dim3 gg(64, 8);
    k_mfma_gemm<0><<<gg, 256, 0, stream>>>(xhi, xlo, WvH, WvL, z);
    k_fft<<<2048, 256, 0, stream>>>(z, G, wsc);
    dim3 gv(32, 16, 4);
    k_vsplit<<<gv, 256, 0, stream>>>(z, vhi, vlo);
    k_mfma_gemm<1><<<gg, 256, 0, stream>>>(vhi, vlo, WoH, WoL, outp);
}

// Round 6
// 200.533 us; speedup vs baseline: 5.0394x; 1.3021x over previous
//
#include <hip/hip_runtime.h>
#include <math.h>

typedef unsigned short u16;
typedef short bf16x8 __attribute__((ext_vector_type(8)));
typedef float f32x4 __attribute__((ext_vector_type(4)));
typedef u16 u16x8 __attribute__((ext_vector_type(8)));

#define B_ 4
#define L_ 2048
#define D_ 1024
#define H_ 16
#define DH 64
#define NF 1025
#define BH (B_*H_)

// ---- workspace layout (in floats) ----
#define Z_OFF    0
#define G_OFF    8388608
#define WSC_OFF  (G_OFF + 262144)
#define XB_OFF   (WSC_OFF + 4096)
#define PART_OFF (XB_OFF + 4096)
#define H1_OFF   (PART_OFF + 131072)
#define QP_OFF   (H1_OFF + 16384)
#define XHI_OFF  (QP_OFF + 32768)
#define XLO_OFF  (XHI_OFF + 4194304)
#define WVH_OFF  (XLO_OFF + 4194304)
#define WVL_OFF  (WVH_OFF + 524288)
#define WOH_OFF  (WVL_OFF + 524288)
#define WOL_OFF  (WOH_OFF + 524288)

__device__ __forceinline__ u16 f2bf(float f) {
    unsigned u = __float_as_uint(f);
    unsigned r = u + 0x7FFFu + ((u >> 16) & 1u);
    return (u16)(r >> 16);
}
__device__ __forceinline__ float bf2f(u16 h) { return __uint_as_float(((unsigned)h) << 16); }

// ---------------- xbar = mean over L of x ----------------
__global__ void k_xbar1(const float* __restrict__ x, float* __restrict__ part) {
    int t = threadIdx.x;
    int dblk = blockIdx.x, lc = blockIdx.y, b = blockIdx.z;
    int d = dblk*256 + t;
    const float* px = x + ((size_t)b*L_ + (size_t)lc*64)*D_ + d;
    float s = 0.f;
    #pragma unroll 4
    for (int l = 0; l < 64; ++l) s += px[(size_t)l*D_];
    part[(size_t)(b*32 + lc)*D_ + d] = s;
}

__global__ void k_xbar2(const float* __restrict__ part, float* __restrict__ xbar) {
    int id = blockIdx.x*256 + threadIdx.x;
    int b = id >> 10, d = id & 1023;
    float s = 0.f;
    for (int c = 0; c < 32; ++c) s += part[(size_t)(b*32 + c)*D_ + d];
    xbar[id] = s * (1.0f/(float)L_);
}

// ---------------- q_mean stage 1 ----------------
__global__ void k_qmean1(const float* __restrict__ xbar, const float* __restrict__ Wq,
                         float* __restrict__ qpart) {
    int t = threadIdx.x;
    int dblk = blockIdx.x, b = blockIdx.y, kc = blockIdx.z;
    int d = dblk*256 + t;
    const float* xb = xbar + b*D_ + kc*128;
    const float* wq = Wq + (size_t)(kc*128)*D_ + d;
    float s = 0.f;
    #pragma unroll 8
    for (int k = 0; k < 128; ++k) s += xb[k] * wq[(size_t)k*D_];
    qpart[((size_t)kc*B_ + b)*D_ + d] = s;
}

// ---------------- gates part A ----------------
__global__ void k_gates_a(const float* __restrict__ qpart,
                          const float* __restrict__ g_ln_w, const float* __restrict__ g_ln_b,
                          const float* __restrict__ g_w1,  const float* __restrict__ g_b1,
                          const float* __restrict__ w_ln_w, const float* __restrict__ w_ln_b,
                          const float* __restrict__ w_w1,  const float* __restrict__ w_b1,
                          const float* __restrict__ w_w2,  const float* __restrict__ w_b2,
                          float* __restrict__ h1_out, float* __restrict__ wscale) {
    int bh = blockIdx.x;
    int b = bh >> 4, h = bh & 15;
    int t = threadIdx.x;
    __shared__ float qm[64], hg[64], wh[64], w1o[64];

    if (t < 64) {
        float s = 0.f;
        #pragma unroll
        for (int kc = 0; kc < 8; ++kc)
            s += qpart[((size_t)kc*B_ + b)*D_ + h*64 + t];
        qm[t] = s;
    }
    __syncthreads();

    float m = 0.f;
    #pragma unroll
    for (int k = 0; k < 64; ++k) m += qm[k];
    m *= (1.0f/64.0f);
    float var = 0.f;
    #pragma unroll
    for (int k = 0; k < 64; ++k) { float df = qm[k]-m; var += df*df; }
    var *= (1.0f/64.0f);
    float rs = rsqrtf(var + 1e-5f);
    if (t < 64) {
        float c = (qm[t]-m)*rs;
        hg[t] = c*g_ln_w[t] + g_ln_b[t];
        wh[t] = c*w_ln_w[t] + w_ln_b[t];
    }
    __syncthreads();

    {
        float acc = g_b1[t];
        #pragma unroll 16
        for (int k = 0; k < 64; ++k) acc += hg[k]*g_w1[k*256 + t];
        h1_out[bh*256 + t] = 0.5f*acc*(1.0f + erff(acc*0.70710678118654752f));
    }
    if (t < 64) {
        float acc = w_b1[t];
        #pragma unroll 16
        for (int k = 0; k < 64; ++k) acc += wh[k]*w_w1[k*64 + t];
        w1o[t] = 0.5f*acc*(1.0f + erff(acc*0.70710678118654752f));
    }
    __syncthreads();

    if (t < 64) {
        float acc = w_b2[t];
        #pragma unroll 16
        for (int k = 0; k < 64; ++k) acc += w1o[k]*w_w2[k*64 + t];
        wscale[bh*64 + t] = 1.0f + 1.0f/(1.0f + expf(-acc));
    }
}

// ---------------- gates part B ----------------
__global__ __launch_bounds__(256) void k_gate_g(const float* __restrict__ h1_ws,
                                                const float* __restrict__ g_w2,
                                                const float* __restrict__ g_b2,
                                                const float* __restrict__ mod_bias,
                                                float* __restrict__ G) {
    int bh = blockIdx.y;
    int f = blockIdx.x*256 + threadIdx.x;
    __shared__ float h1[256];
    h1[threadIdx.x] = h1_ws[bh*256 + threadIdx.x];
    __syncthreads();
    if (f >= NF) return;

    float re = g_b2[f], im = g_b2[NF + f];
    #pragma unroll 4
    for (int k = 0; k < 256; ++k) {
        float hv = h1[k];
        re += hv*g_w2[(size_t)k*2050 + f];
        im += hv*g_w2[(size_t)k*2050 + NF + f];
    }
    float mag = sqrtf(re*re + im*im);
    float mult = fmaxf(mag + mod_bias[f], 0.f) / (mag + 1e-6f);
    float s = mult * (1.0f/2048.0f);
    float gr = s*re, gi = s*im;
    if (f == 0 || f == 1024) gi = 0.f;
    float* Gb = G + (size_t)bh*4096;
    Gb[2*f]   = gr;
    Gb[2*f+1] = gi;
    if (f >= 1 && f <= 1023) {
        Gb[2*(2048-f)]   = gr;
        Gb[2*(2048-f)+1] = -gi;
    }
}

// ---------------- x -> bf16 hi/lo split ----------------
__global__ void k_xsplit(const float4* __restrict__ x, u16* __restrict__ hi, u16* __restrict__ lo) {
    int i = blockIdx.x*256 + threadIdx.x;
    float4 v = x[i];
    ushort4 h, l;
    h.x = f2bf(v.x); l.x = f2bf(v.x - bf2f(h.x));
    h.y = f2bf(v.y); l.y = f2bf(v.y - bf2f(h.y));
    h.z = f2bf(v.z); l.z = f2bf(v.z - bf2f(h.z));
    h.w = f2bf(v.w); l.w = f2bf(v.w - bf2f(h.w));
    ((ushort4*)hi)[i] = h;
    ((ushort4*)lo)[i] = l;
}

// ---------------- weight transpose + bf16 hi/lo split ----------------
__global__ void k_wsplit(const float* __restrict__ Wv, const float* __restrict__ Wo,
                         u16* __restrict__ WvH, u16* __restrict__ WvL,
                         u16* __restrict__ WoH, u16* __restrict__ WoL) {
    const float* W = blockIdx.z ? Wo : Wv;
    u16* TH = blockIdx.z ? WoH : WvH;
    u16* TL = blockIdx.z ? WoL : WvL;
    __shared__ float tile[32][33];
    int t = threadIdx.x;
    int n0 = blockIdx.x*32, k0 = blockIdx.y*32;
    #pragma unroll
    for (int i = 0; i < 4; ++i) {
        int k = (t >> 5) + 8*i;
        tile[k][t & 31] = W[(size_t)(k0 + k)*D_ + n0 + (t & 31)];
    }
    __syncthreads();
    int n = t >> 3, kc = (t & 7)*4;
    float f0 = tile[kc+0][n], f1 = tile[kc+1][n], f2 = tile[kc+2][n], f3 = tile[kc+3][n];
    ushort4 h, l;
    h.x = f2bf(f0); l.x = f2bf(f0 - bf2f(h.x));
    h.y = f2bf(f1); l.y = f2bf(f1 - bf2f(h.y));
    h.z = f2bf(f2); l.z = f2bf(f2 - bf2f(h.z));
    h.w = f2bf(f3); l.w = f2bf(f3 - bf2f(h.w));
    *(ushort4*)&TH[(size_t)(n0 + n)*D_ + k0 + kc] = h;
    *(ushort4*)&TL[(size_t)(n0 + n)*D_ + k0 + kc] = l;
}

// ---------------- fused bf16x3 MFMA GEMM with XOR-swizzled LDS ----------------
__device__ __forceinline__ void stage4(const u16* __restrict__ gbase, u16* lds, int t) {
    #pragma unroll
    for (int i = 0; i < 4; ++i) {
        int c = t + i*256;
        int r = c >> 3, cs = c & 7;
        int ko = (cs ^ (r & 7)) << 3;
        __builtin_amdgcn_global_load_lds(
            (const __attribute__((address_space(1))) void*)(gbase + (size_t)r*D_ + ko),
            (__attribute__((address_space(3))) void*)(lds + c*8), 16, 0, 0);
    }
}

template<int EPI>
__global__ __launch_bounds__(256) void k_mfma_gemm(const u16* __restrict__ Ahi, const u16* __restrict__ Alo,
                                                   const u16* __restrict__ Bhi, const u16* __restrict__ Blo,
                                                   float* __restrict__ C) {
    __shared__ u16 AsH[128*64], AsL[128*64], BsH[128*64], BsL[128*64];
    int t = threadIdx.x;
    size_t rowBase = (size_t)blockIdx.x * 128;
    int colBase = blockIdx.y * 128;
    f32x4 acc[4][4] = {};
    int lane = t & 63;
    int wr = (t >> 7) & 1, wc = (t >> 6) & 1;
    int lr = lane & 15, lq = lane >> 4;

    for (int k0 = 0; k0 < 1024; k0 += 64) {
        stage4(Ahi + rowBase*D_ + k0, AsH, t);
        stage4(Alo + rowBase*D_ + k0, AsL, t);
        stage4(Bhi + (size_t)colBase*D_ + k0, BsH, t);
        stage4(Blo + (size_t)colBase*D_ + k0, BsL, t);
        __syncthreads();
        #pragma unroll
        for (int ks = 0; ks < 2; ++ks) {
            bf16x8 ah[4], al[4], bh[4], bl[4];
            #pragma unroll
            for (int m = 0; m < 4; ++m) {
                int row = wr*64 + m*16 + lr;
                int ch = (ks*4 + lq) ^ (row & 7);
                ah[m] = *(const bf16x8*)(AsH + row*64 + ch*8);
                al[m] = *(const bf16x8*)(AsL + row*64 + ch*8);
            }
            #pragma unroll
            for (int n = 0; n < 4; ++n) {
                int row = wc*64 + n*16 + lr;
                int ch = (ks*4 + lq) ^ (row & 7);
                bh[n] = *(const bf16x8*)(BsH + row*64 + ch*8);
                bl[n] = *(const bf16x8*)(BsL + row*64 + ch*8);
            }
            #pragma unroll
            for (int m = 0; m < 4; ++m) {
                #pragma unroll
                for (int n = 0; n < 4; ++n) {
                    acc[m][n] = __builtin_amdgcn_mfma_f32_16x16x32_bf16(ah[m], bh[n], acc[m][n], 0, 0, 0);
                    acc[m][n] = __builtin_amdgcn_mfma_f32_16x16x32_bf16(ah[m], bl[n], acc[m][n], 0, 0, 0);
                    acc[m][n] = __builtin_amdgcn_mfma_f32_16x16x32_bf16(al[m], bh[n], acc[m][n], 0, 0, 0);
                }
            }
        }
        __syncthreads();
    }

    int cr = lq * 4, cc = lane & 15;
    if (EPI == 0) {
        #pragma unroll
        for (int m = 0; m < 4; ++m) {
            #pragma unroll
            for (int n = 0; n < 4; ++n) {
                int d = colBase + wc*64 + n*16 + cc;
                int hh = d >> 6, pr = (d >> 1) & 31, p = d & 1;
                #pragma unroll
                for (int r = 0; r < 4; ++r) {
                    size_t gr = rowBase + wr*64 + m*16 + cr + r;
                    int b = (int)(gr >> 11), l = (int)(gr & 2047);
                    C[(((size_t)((b*16 + hh)*32 + pr))*L_ + l)*2 + p] = acc[m][n][r];
                }
            }
        }
    } else {
        #pragma unroll
        for (int m = 0; m < 4; ++m) {
            #pragma unroll
            for (int n = 0; n < 4; ++n) {
                int d = colBase + wc*64 + n*16 + cc;
                #pragma unroll
                for (int r = 0; r < 4; ++r) {
                    size_t gr = rowBase + wr*64 + m*16 + cr + r;
                    C[gr*D_ + d] = acc[m][n][r];
                }
            }
        }
    }
}

// ---------------- register radix-8 FFT-2048 ----------------
__device__ __forceinline__ float2 cmulp(float2 a, float2 b) {
    return make_float2(a.x*b.x - a.y*b.y, a.x*b.y + a.y*b.x);
}
__device__ __forceinline__ float2 cadd(float2 a, float2 b){ return make_float2(a.x+b.x, a.y+b.y); }
__device__ __forceinline__ float2 csub(float2 a, float2 b){ return make_float2(a.x-b.x, a.y-b.y); }
__device__ __forceinline__ float2 cnegi(float2 a){ return make_float2(a.y, -a.x); }   // a * (-i)
__device__ __forceinline__ float2 cposi(float2 a){ return make_float2(-a.y, a.x); }   // a * (+i)

#define RH_ 0.70710678118654752f

// forward DIF: 3 stages on 8 elems at stride s, base twiddle w1 = W^(off_base*1024/(4s))
__device__ __forceinline__ void fwd3(float2* e, float2 w1) {
    float2 tA1 = make_float2((w1.x + w1.y)*RH_, (w1.y - w1.x)*RH_);   // w1*e^{-i pi/4}
    float2 tA2 = cnegi(w1);
    float2 tA3 = make_float2((w1.y - w1.x)*RH_, -(w1.x + w1.y)*RH_);  // w1*e^{-3i pi/4}
    float2 a, b, d;
    a=e[0]; b=e[4]; e[0]=cadd(a,b); d=csub(a,b); e[4]=cmulp(d, w1);
    a=e[1]; b=e[5]; e[1]=cadd(a,b); d=csub(a,b); e[5]=cmulp(d, tA1);
    a=e[2]; b=e[6]; e[2]=cadd(a,b); d=csub(a,b); e[6]=cmulp(d, tA2);
    a=e[3]; b=e[7]; e[3]=cadd(a,b); d=csub(a,b); e[7]=cmulp(d, tA3);
    float2 w2 = cmulp(w1,w1); float2 w2n = cnegi(w2);
    a=e[0]; b=e[2]; e[0]=cadd(a,b); d=csub(a,b); e[2]=cmulp(d, w2);
    a=e[1]; b=e[3]; e[1]=cadd(a,b); d=csub(a,b); e[3]=cmulp(d, w2n);
    a=e[4]; b=e[6]; e[4]=cadd(a,b); d=csub(a,b); e[6]=cmulp(d, w2);
    a=e[5]; b=e[7]; e[5]=cadd(a,b); d=csub(a,b); e[7]=cmulp(d, w2n);
    float2 w4 = cmulp(w2,w2);
    a=e[0]; b=e[1]; e[0]=cadd(a,b); d=csub(a,b); e[1]=cmulp(d, w4);
    a=e[2]; b=e[3]; e[2]=cadd(a,b); d=csub(a,b); e[3]=cmulp(d, w4);
    a=e[4]; b=e[5]; e[4]=cadd(a,b); d=csub(a,b); e[5]=cmulp(d, w4);
    a=e[6]; b=e[7]; e[6]=cadd(a,b); d=csub(a,b); e[7]=cmulp(d, w4);
}

// inverse DIT: 3 stages on 8 elems at stride s, base twiddle b1 = conj(W)^(off_base*1024/(4s))
__device__ __forceinline__ void inv3(float2* e, float2 b1) {
    float2 b2 = cmulp(b1,b1), b4 = cmulp(b2,b2);
    float2 a, bb;
    bb=cmulp(e[1],b4); a=e[0]; e[0]=cadd(a,bb); e[1]=csub(a,bb);
    bb=cmulp(e[3],b4); a=e[2]; e[2]=cadd(a,bb); e[3]=csub(a,bb);
    bb=cmulp(e[5],b4); a=e[4]; e[4]=cadd(a,bb); e[5]=csub(a,bb);
    bb=cmulp(e[7],b4); a=e[6]; e[6]=cadd(a,bb); e[7]=csub(a,bb);
    float2 b2i = cposi(b2);
    bb=cmulp(e[2],b2);  a=e[0]; e[0]=cadd(a,bb); e[2]=csub(a,bb);
    bb=cmulp(e[3],b2i); a=e[1]; e[1]=cadd(a,bb); e[3]=csub(a,bb);
    bb=cmulp(e[6],b2);  a=e[4]; e[4]=cadd(a,bb); e[6]=csub(a,bb);
    bb=cmulp(e[7],b2i); a=e[5]; e[5]=cadd(a,bb); e[7]=csub(a,bb);
    float2 tB1 = make_float2((b1.x - b1.y)*RH_, (b1.x + b1.y)*RH_);   // b1*e^{+i pi/4}
    float2 tB2 = cposi(b1);
    float2 tB3 = make_float2(-(b1.x + b1.y)*RH_, (b1.x - b1.y)*RH_);  // b1*e^{+3i pi/4}
    bb=cmulp(e[4],b1);  a=e[0]; e[0]=cadd(a,bb); e[4]=csub(a,bb);
    bb=cmulp(e[5],tB1); a=e[1]; e[1]=cadd(a,bb); e[5]=csub(a,bb);
    bb=cmulp(e[6],tB2); a=e[2]; e[2]=cadd(a,bb); e[6]=csub(a,bb);
    bb=cmulp(e[7],tB3); a=e[3]; e[3]=cadd(a,bb); e[7]=csub(a,bb);
}

// inverse DIT: 2 stages on 4 elems at stride 512, base b1 = conj(W)^c
__device__ __forceinline__ void inv2(float2* e, float2 b1) {
    float2 b2 = cmulp(b1,b1);
    float2 a, bb;
    bb=cmulp(e[1],b2); a=e[0]; e[0]=cadd(a,bb); e[1]=csub(a,bb);
    bb=cmulp(e[3],b2); a=e[2]; e[2]=cadd(a,bb); e[3]=csub(a,bb);
    float2 b1i = cposi(b1);
    bb=cmulp(e[2],b1);  a=e[0]; e[0]=cadd(a,bb); e[2]=csub(a,bb);
    bb=cmulp(e[3],b1i); a=e[1]; e[1]=cadd(a,bb); e[3]=csub(a,bb);
}

#define PIDX(i) ((i) + ((i)>>5))

__global__ __launch_bounds__(256, 8) void k_fft(float* __restrict__ z,
                                                const float* __restrict__ G,
                                                const float* __restrict__ wscale) {
    __shared__ float2 dsh[2112];
    int t = threadIdx.x;
    int row = blockIdx.x;
    int bh = row >> 5, jp = row & 31;
    float2* zr = (float2*)z + (size_t)row * L_;
    const float PIO = 3.14159265358979323846f;

    float2 e[8];
    // ---- P1: stages 1024,512,256 (stride 256), read global ----
    #pragma unroll
    for (int j = 0; j < 8; ++j) e[j] = zr[t + 256*j];
    {
        float s_, c_; sincosf(-(PIO/1024.f)*(float)t, &s_, &c_);
        fwd3(e, make_float2(c_, s_));
    }
    #pragma unroll
    for (int j = 0; j < 8; ++j) { int i = t + 256*j; dsh[PIDX(i)] = e[j]; }
    __syncthreads();

    // ---- P2: stages 128,64,32 (stride 32) ----
    {
        int q = t >> 5, r = t & 31, base = q*256 + r;
        #pragma unroll
        for (int j = 0; j < 8; ++j) { int i = base + 32*j; e[j] = dsh[PIDX(i)]; }
        float s_, c_; sincosf(-(PIO/128.f)*(float)r, &s_, &c_);
        fwd3(e, make_float2(c_, s_));
        #pragma unroll
        for (int j = 0; j < 8; ++j) { int i = base + 32*j; dsh[PIDX(i)] = e[j]; }
    }
    __syncthreads();

    // ---- P3: stages 16,8,4 (stride 4) ----
    {
        int q = t >> 2, r = t & 3, base = q*32 + r;
        #pragma unroll
        for (int j = 0; j < 8; ++j) { int i = base + 4*j; e[j] = dsh[PIDX(i)]; }
        float s_, c_; sincosf(-(PIO/16.f)*(float)r, &s_, &c_);
        fwd3(e, make_float2(c_, s_));
        #pragma unroll
        for (int j = 0; j < 8; ++j) { int i = base + 4*j; dsh[PIDX(i)] = e[j]; }
    }
    __syncthreads();

    // ---- P4 (stages 2,1) + gate + invA (stages 1,2,4), stride 1, positions 8t+u ----
    {
        #pragma unroll
        for (int u = 0; u < 8; ++u) { int i = 8*t + u; e[u] = dsh[PIDX(i)]; }
        float2 a, b, d;
        a=e[0]; b=e[2]; e[0]=cadd(a,b); e[2]=csub(a,b);
        a=e[1]; b=e[3]; e[1]=cadd(a,b); d=csub(a,b); e[3]=cnegi(d);
        a=e[4]; b=e[6]; e[4]=cadd(a,b); e[6]=csub(a,b);
        a=e[5]; b=e[7]; e[5]=cadd(a,b); d=csub(a,b); e[7]=cnegi(d);
        a=e[0]; b=e[1]; e[0]=cadd(a,b); e[1]=csub(a,b);
        a=e[2]; b=e[3]; e[2]=cadd(a,b); e[3]=csub(a,b);
        a=e[4]; b=e[5]; e[4]=cadd(a,b); e[5]=csub(a,b);
        a=e[6]; b=e[7]; e[6]=cadd(a,b); e[7]=csub(a,b);
        // gate in bit-reversed domain: pos 8t+u holds X[brev8(t) + 256*brev3(u)]
        int flo = (int)(__brev((unsigned)t) >> 24);
        const float2* Gb = (const float2*)(G + (size_t)bh*4096);
        e[0] = cmulp(e[0], Gb[flo + 256*0]);
        e[1] = cmulp(e[1], Gb[flo + 256*4]);
        e[2] = cmulp(e[2], Gb[flo + 256*2]);
        e[3] = cmulp(e[3], Gb[flo + 256*6]);
        e[4] = cmulp(e[4], Gb[flo + 256*1]);
        e[5] = cmulp(e[5], Gb[flo + 256*5]);
        e[6] = cmulp(e[6], Gb[flo + 256*3]);
        e[7] = cmulp(e[7], Gb[flo + 256*7]);
        inv3(e, make_float2(1.f, 0.f));
        #pragma unroll
        for (int u = 0; u < 8; ++u) { int i = 8*t + u; dsh[PIDX(i)] = e[u]; }
    }
    __syncthreads();

    // ---- invB: stages 8,16,32 (stride 8) ----
    {
        int q = t >> 3, r = t & 7, base = q*64 + r;
        #pragma unroll
        for (int j = 0; j < 8; ++j) { int i = base + 8*j; e[j] = dsh[PIDX(i)]; }
        float s_, c_; sincosf((PIO/32.f)*(float)r, &s_, &c_);
        inv3(e, make_float2(c_, s_));
        #pragma unroll
        for (int j = 0; j < 8; ++j) { int i = base + 8*j; dsh[PIDX(i)] = e[j]; }
    }
    __syncthreads();

    // ---- invC: stages 64,128,256 (stride 64) ----
    {
        int q = t >> 6, r = t & 63, base = q*512 + r;
        #pragma unroll
        for (int j = 0; j < 8; ++j) { int i = base + 64*j; e[j] = dsh[PIDX(i)]; }
        float s_, c_; sincosf((PIO/256.f)*(float)r, &s_, &c_);
        inv3(e, make_float2(c_, s_));
        #pragma unroll
        for (int j = 0; j < 8; ++j) { int i = base + 64*j; dsh[PIDX(i)] = e[j]; }
    }
    __syncthreads();

    // ---- invD: stages 512,1024 (stride 512, two 4-groups) + wscale + write ----
    {
        #pragma unroll
        for (int j = 0; j < 4; ++j) { int i = t + 512*j; e[j] = dsh[PIDX(i)]; }
        #pragma unroll
        for (int j = 0; j < 4; ++j) { int i = t + 256 + 512*j; e[4+j] = dsh[PIDX(i)]; }
        float s_, c_; sincosf((PIO/1024.f)*(float)t, &s_, &c_);
        float2 b1 = make_float2(c_, s_);
        inv2(e, b1);
        float2 b1b = make_float2((b1.x - b1.y)*RH_, (b1.x + b1.y)*RH_);  // b1*e^{+i pi/4}
        inv2(e+4, b1b);
        float sc0 = wscale[bh*64 + 2*jp];
        float sc1 = wscale[bh*64 + 2*jp + 1];
        #pragma unroll
        for (int j = 0; j < 4; ++j) zr[t + 512*j] = make_float2(e[j].x*sc0, e[j].y*sc1);
        #pragma unroll
        for (int j = 0; j < 4; ++j) zr[t + 256 + 512*j] = make_float2(e[4+j].x*sc0, e[4+j].y*sc1);
    }
}

// ---------------- z -> vmix [m][d] bf16 hi/lo ----------------
__global__ void k_vsplit(const float* __restrict__ z, u16* __restrict__ vhi, u16* __restrict__ vlo) {
    int t = threadIdx.x;
    int lt = blockIdx.x, h = blockIdx.y, b = blockIdx.z;
    int l0 = lt*64;
    __shared__ float tile[64][65];
    const float2* zb = (const float2*)z + (size_t)(b*16 + h)*32*L_;
    int pr = t >> 3, lg = t & 7;
    #pragma unroll
    for (int i = 0; i < 8; ++i) {
        int l = lg*8 + i;
        float2 v = zb[(size_t)pr*L_ + l0 + l];
        tile[l][2*pr]   = v.x;
        tile[l][2*pr+1] = v.y;
    }
    __syncthreads();
    int l = t >> 2, d0 = (t & 3) * 16;
    u16x8 h0, h1v, l0v, l1v;
    #pragma unroll
    for (int i = 0; i < 8; ++i) {
        float f = tile[l][d0+i];
        u16 hb = f2bf(f);
        h0[i] = hb; l0v[i] = f2bf(f - bf2f(hb));
    }
    #pragma unroll
    for (int i = 0; i < 8; ++i) {
        float f = tile[l][d0+8+i];
        u16 hb = f2bf(f);
        h1v[i] = hb; l1v[i] = f2bf(f - bf2f(hb));
    }
    size_t base = ((size_t)(b*L_) + l0 + l)*D_ + h*64 + d0;
    *(u16x8*)&vhi[base]   = h0;
    *(u16x8*)&vhi[base+8] = h1v;
    *(u16x8*)&vlo[base]   = l0v;
    *(u16x8*)&vlo[base+8] = l1v;
}

extern "C" void kernel_launch(void* const* d_in, const int* in_sizes, int n_in,
                              void* d_out, int out_size, void* d_ws, size_t ws_size,
                              hipStream_t stream) {
    const float* x      = (const float*)d_in[0];
    const float* Wq     = (const float*)d_in[1];
    const float* Wv     = (const float*)d_in[2];
    const float* Wo     = (const float*)d_in[3];
    const float* g_ln_w = (const float*)d_in[4];
    const float* g_ln_b = (const float*)d_in[5];
    const float* g_w1   = (const float*)d_in[6];
    const float* g_b1   = (const float*)d_in[7];
    const float* g_w2   = (const float*)d_in[8];
    const float* g_b2   = (const float*)d_in[9];
    const float* mod_b  = (const float*)d_in[10];
    const float* w_ln_w = (const float*)d_in[11];
    const float* w_ln_b = (const float*)d_in[12];
    const float* w_w1   = (const float*)d_in[13];
    const float* w_b1   = (const float*)d_in[14];
    const float* w_w2   = (const float*)d_in[15];
    const float* w_b2   = (const float*)d_in[16];

    float* ws   = (float*)d_ws;
    float* z    = ws + Z_OFF;
    float* G    = ws + G_OFF;
    float* wsc  = ws + WSC_OFF;
    float* xbar = ws + XB_OFF;
    float* part = ws + PART_OFF;
    float* h1ws = ws + H1_OFF;
    float* qpart= ws + QP_OFF;
    u16* xhi = (u16*)(ws + XHI_OFF);
    u16* xlo = (u16*)(ws + XLO_OFF);
    u16* WvH = (u16*)(ws + WVH_OFF);
    u16* WvL = (u16*)(ws + WVL_OFF);
    u16* WoH = (u16*)(ws + WOH_OFF);
    u16* WoL = (u16*)(ws + WOL_OFF);
    u16* vhi = xhi;
    u16* vlo = xlo;
    float* outp = (float*)d_out;

    dim3 gx(4, 32, 4);
    k_xbar1<<<gx, 256, 0, stream>>>(x, part);
    k_xbar2<<<16, 256, 0, stream>>>(part, xbar);
    dim3 gq(4, 4, 8);
    k_qmean1<<<gq, 256, 0, stream>>>(xbar, Wq, qpart);
    k_gates_a<<<64, 256, 0, stream>>>(qpart, g_ln_w, g_ln_b, g_w1, g_b1,
                                      w_ln_w, w_ln_b, w_w1, w_b1, w_w2, w_b2,
                                      h1ws, wsc);
    dim3 ggate(5, 64);
    k_gate_g<<<ggate, 256, 0, stream>>>(h1ws, g_w2, g_b2, mod_b, G);
    k_xsplit<<<8192, 256, 0, stream>>>((const float4*)x, xhi, xlo);
    dim3 gw(32, 32, 2);
    k_wsplit<<<gw, 256, 0, stream>>>(Wv, Wo, WvH, WvL, WoH, WoL);

    dim3 gg(64, 8);
    k_mfma_gemm<0><<<gg, 256, 0, stream>>>(xhi, xlo, WvH, WvL, z);
    k_fft<<<2048, 256, 0, stream>>>(z, G, wsc);
    dim3 gv(32, 16, 4);
    k_vsplit<<<gv, 256, 0, stream>>>(z, vhi, vlo);
    k_mfma_gemm<1><<<gg, 256, 0, stream>>>(vhi, vlo, WoH, WoL, outp);
}